// Round 1
// baseline (353.112 us; speedup 1.0000x reference)
//
#include <hip/hip_runtime.h>
#include <stdint.h>

#define NPTS 4096
#define NB   4
#define KNN  32
#define NKPT 15

// workspace byte offsets (all 256B-aligned)
#define OFF_IDX      0ULL            // 4*4096*32*4        = 2,097,152
#define OFF_FEAT0    2097152ULL      // 4*4097*64*4        = 4,195,328
#define OFF_WEIGHTED 6292480ULL      // 16384*960*4        = 62,914,560
#define OFF_ROUT0    69207040ULL     // 16384*64*4         = 4,194,304
#define OFF_F1T      73401344ULL     // 65,536
#define OFF_F2T      73466880ULL     // 65,536  (end 73,532,416)

// d_out float offsets
#define OUT_OFF_OUT  0
#define OUT_OFF_KP   1048576
#define OUT_OFF_FUSE 1048621

// ---------------- K0: transposes, shadow row, kp copy ----------------
__global__ __launch_bounds__(256) void k0_init(const float* __restrict__ f1_w,
                                               const float* __restrict__ f2_w,
                                               const float* __restrict__ kp_pos,
                                               float* __restrict__ f1t,
                                               float* __restrict__ f2t,
                                               float* __restrict__ feat0,
                                               float* __restrict__ out_kp) {
  int t = blockIdx.x * 256 + threadIdx.x;
  if (t < 16384) { int c = t >> 7, o = t & 127; f1t[c * 128 + o] = f1_w[o * 128 + c]; return; }
  t -= 16384;
  if (t < 16384) { int c = t >> 7, o = t & 127; f2t[c * 128 + o] = f2_w[o * 128 + c]; return; }
  t -= 16384;
  if (t < NB * 64) { int b = t >> 6, d = t & 63; feat0[((size_t)b * (NPTS + 1) + NPTS) * 64 + d] = 0.f; return; }
  t -= NB * 64;
  if (t < 45) out_kp[t] = kp_pos[t];
}

// ---------------- K1: ball query, first-32-by-index, f64 distances ----------------
__global__ __launch_bounds__(256) void k1_neigh(const float* __restrict__ pos,
                                                int* __restrict__ idx_ws) {
  const int w = threadIdx.x >> 6, lane = threadIdx.x & 63;
  const int pt = blockIdx.x * 4 + w;
  const int b = pt >> 12, n = pt & 4095;
  const float* px = pos + (size_t)b * 3 * NPTS;
  const double x0 = (double)px[n], y0 = (double)px[NPTS + n], z0 = (double)px[2 * NPTS + n];
  const double ssrc = x0 * x0 + y0 * y0 + z0 * z0;
  const double RAD = 0.1 * 2.0;
  const double R2 = RAD * RAD;
  int cnt = 0;
  int* op = idx_ws + (size_t)pt * KNN;
  for (int ch = 0; ch < 64; ++ch) {
    const int j = ch * 64 + lane;
    const double xj = (double)px[j], yj = (double)px[NPTS + j], zj = (double)px[2 * NPTS + j];
    const double dot  = x0 * xj + y0 * yj + z0 * zj;
    const double sdst = xj * xj + yj * yj + zj * zj;
    const double sq = -2.0 * dot + ssrc + sdst;
    const bool keep = !(sq > R2);
    const unsigned long long m = __ballot(keep);
    if (keep) {
      const int p = cnt + (int)__popcll(m & ((1ULL << lane) - 1ULL));
      if (p < KNN) op[p] = j;
    }
    cnt += (int)__popcll(m);
    if (cnt >= KNN) break;
  }
  const int s = cnt + lane;
  if (s < KNN) op[s] = NPTS;
}

// ---------------- K2: feat0 = cb_w @ feat + cb_b, stored [B][N+1][64] ----------------
__global__ __launch_bounds__(256) void k2_feat0(const float* __restrict__ feat,
                                                const float* __restrict__ cb_w,
                                                const float* __restrict__ cb_b,
                                                float* __restrict__ feat0) {
  __shared__ float cbt[64 * 65];  // cbt[c][d] padded
  const int t = threadIdx.x;
  #pragma unroll
  for (int q = 0; q < 16; ++q) {
    const int idx = q * 256 + t;
    const int d = idx >> 6, c = idx & 63;
    cbt[c * 65 + d] = cb_w[idx];
  }
  __syncthreads();
  const int ptl = t >> 6, d = t & 63;
  const int pt = blockIdx.x * 4 + ptl;
  const int b = pt >> 12, n = pt & 4095;
  const float* fp = feat + (size_t)b * 64 * NPTS + n;
  float acc = 0.f;
  #pragma unroll
  for (int c = 0; c < 64; ++c) acc = fmaf(cbt[c * 65 + d], fp[(size_t)c * NPTS], acc);
  acc += cb_b[d];
  feat0[((size_t)b * (NPTS + 1) + n) * 64 + d] = acc;
}

// ---------------- K3: gather + kernel-point weights + weighted [16384][15][64] ----------------
__global__ __launch_bounds__(64) void k3_weighted(const float* __restrict__ pos,
                                                  const int* __restrict__ idx_ws,
                                                  const float* __restrict__ feat0,
                                                  const float* __restrict__ kp_pos,
                                                  float* __restrict__ weighted) {
  __shared__ int   nidx[KNN];
  __shared__ float npx[KNN], npy[KNN], npz[KNN];
  __shared__ float kp[48];
  __shared__ float wl[KNN * 16];  // wl[k][p], p padded to 16
  const int lane = threadIdx.x;
  const int pt = blockIdx.x;
  const int b = pt >> 12;
  if (lane < 45) kp[lane] = kp_pos[lane];
  if (lane < KNN) {
    const int ki = idx_ws[(size_t)pt * KNN + lane];
    nidx[lane] = ki;
    const bool v = ki < NPTS;
    const float* px = pos + (size_t)b * 3 * NPTS;
    npx[lane] = v ? px[ki] : 1000000.0f;
    npy[lane] = v ? px[NPTS + ki] : 1000000.0f;
    npz[lane] = v ? px[2 * NPTS + ki] : 1000000.0f;
  }
  __syncthreads();
  #pragma unroll
  for (int r = 0; r < 8; ++r) {
    const int i = r * 64 + lane;
    const int k = i >> 4, p = i & 15;
    float wv = 0.f;
    if (p < 15) {
      const float dx = npx[k] - kp[p];
      const float dy = npy[k] - kp[15 + p];
      const float dz = npz[k] - kp[30 + p];
      const float d2 = dx * dx + dy * dy + dz * dz;
      wv = fmaxf(1.0f - sqrtf(d2) / 1.2f, 0.f);
    }
    wl[i] = wv;
  }
  __syncthreads();
  float acc[16];
  #pragma unroll
  for (int p = 0; p < 16; ++p) acc[p] = 0.f;
  const float* f0 = feat0 + (size_t)b * (NPTS + 1) * 64 + lane;
  for (int k = 0; k < KNN; ++k) {
    const float f = f0[(size_t)nidx[k] * 64];
    #pragma unroll
    for (int q = 0; q < 4; ++q) {
      const float4 w4 = *(const float4*)&wl[k * 16 + q * 4];
      acc[q * 4 + 0] = fmaf(w4.x, f, acc[q * 4 + 0]);
      acc[q * 4 + 1] = fmaf(w4.y, f, acc[q * 4 + 1]);
      acc[q * 4 + 2] = fmaf(w4.z, f, acc[q * 4 + 2]);
      acc[q * 4 + 3] = fmaf(w4.w, f, acc[q * 4 + 3]);
    }
  }
  float* wp = weighted + (size_t)pt * NKPT * 64 + lane;
  #pragma unroll
  for (int p = 0; p < 15; ++p) wp[(size_t)p * 64] = acc[p];
}

// ---------------- K4: rout0 = relu(weighted[16384x960] @ kpw[960x64] + bias) ----------------
__global__ __launch_bounds__(256) void k4_kpconv(const float* __restrict__ weighted,
                                                 const float* __restrict__ kpw,
                                                 const float* __restrict__ kp_bias,
                                                 float* __restrict__ rout0) {
  __shared__ float Ast[64 * 36];  // Ast[kk][m], m padded 32->36
  __shared__ float Bs[64 * 64];   // Bs[kk][d]
  const int t = threadIdx.x;
  const int m0 = blockIdx.x * 32;
  const int tm = t >> 4, td = t & 15;
  float acc[2][4] = {};
  for (int ch = 0; ch < 15; ++ch) {
    const int k0 = ch * 64;
    __syncthreads();
    {
      const int base = t * 8;
      const int mA = base >> 6;
      const int kA = base & 63;
      #pragma unroll
      for (int q = 0; q < 2; ++q) {
        const float4 v = *(const float4*)&weighted[(size_t)(m0 + mA) * 960 + k0 + kA + q * 4];
        Ast[(kA + q * 4 + 0) * 36 + mA] = v.x;
        Ast[(kA + q * 4 + 1) * 36 + mA] = v.y;
        Ast[(kA + q * 4 + 2) * 36 + mA] = v.z;
        Ast[(kA + q * 4 + 3) * 36 + mA] = v.w;
      }
    }
    #pragma unroll
    for (int q = 0; q < 4; ++q) {
      const int idx = q * 1024 + t * 4;
      const int kk = idx >> 6, d = idx & 63;
      *(float4*)&Bs[kk * 64 + d] = *(const float4*)&kpw[(size_t)(k0 + kk) * 64 + d];
    }
    __syncthreads();
    #pragma unroll 8
    for (int kk = 0; kk < 64; ++kk) {
      const float2 a2 = *(const float2*)&Ast[kk * 36 + tm * 2];
      const float4 b4 = *(const float4*)&Bs[kk * 64 + td * 4];
      acc[0][0] = fmaf(a2.x, b4.x, acc[0][0]);
      acc[0][1] = fmaf(a2.x, b4.y, acc[0][1]);
      acc[0][2] = fmaf(a2.x, b4.z, acc[0][2]);
      acc[0][3] = fmaf(a2.x, b4.w, acc[0][3]);
      acc[1][0] = fmaf(a2.y, b4.x, acc[1][0]);
      acc[1][1] = fmaf(a2.y, b4.y, acc[1][1]);
      acc[1][2] = fmaf(a2.y, b4.z, acc[1][2]);
      acc[1][3] = fmaf(a2.y, b4.w, acc[1][3]);
    }
  }
  const float4 bias = *(const float4*)&kp_bias[td * 4];
  #pragma unroll
  for (int i = 0; i < 2; ++i) {
    const int m = m0 + tm * 2 + i;
    float4 o;
    o.x = fmaxf(acc[i][0] + bias.x, 0.f);
    o.y = fmaxf(acc[i][1] + bias.y, 0.f);
    o.z = fmaxf(acc[i][2] + bias.z, 0.f);
    o.w = fmaxf(acc[i][3] + bias.w, 0.f);
    *(float4*)&rout0[(size_t)m * 64 + td * 4] = o;
  }
}

// ---------------- K5: out = relu(ce_w @ rout0 + ce_b + feat) ----------------
__global__ __launch_bounds__(256) void k5_out(const float* __restrict__ rout0,
                                              const float* __restrict__ ce_w,
                                              const float* __restrict__ ce_b,
                                              const float* __restrict__ feat,
                                              float* __restrict__ out) {
  __shared__ float r0[64 * 65];   // r0[n][c] padded
  __shared__ float cwt[64 * 64];  // cwt[c][o]
  const int t = threadIdx.x;
  const int b = blockIdx.x >> 6;
  const int n0 = (blockIdx.x & 63) * 64;
  #pragma unroll
  for (int q = 0; q < 16; ++q) {
    const int idx = q * 256 + t;
    const int rr = idx >> 6, c = idx & 63;
    r0[rr * 65 + c] = rout0[((size_t)b * 4096 + n0 + rr) * 64 + c];
    cwt[idx] = ce_w[(idx & 63) * 64 + (idx >> 6)];  // cwt[c][o] = ce_w[o][c]
  }
  __syncthreads();
  const int nl = t & 63, og = t >> 6;
  float acc[16];
  #pragma unroll
  for (int j = 0; j < 16; ++j) acc[j] = 0.f;
  for (int c = 0; c < 64; ++c) {
    const float x = r0[nl * 65 + c];
    #pragma unroll
    for (int q = 0; q < 4; ++q) {
      const float4 w4 = *(const float4*)&cwt[c * 64 + og * 16 + q * 4];
      acc[q * 4 + 0] = fmaf(w4.x, x, acc[q * 4 + 0]);
      acc[q * 4 + 1] = fmaf(w4.y, x, acc[q * 4 + 1]);
      acc[q * 4 + 2] = fmaf(w4.z, x, acc[q * 4 + 2]);
      acc[q * 4 + 3] = fmaf(w4.w, x, acc[q * 4 + 3]);
    }
  }
  #pragma unroll
  for (int q = 0; q < 4; ++q) {
    const float4 cb4 = *(const float4*)&ce_b[og * 16 + q * 4];
    const float cbv[4] = {cb4.x, cb4.y, cb4.z, cb4.w};
    #pragma unroll
    for (int j = 0; j < 4; ++j) {
      const int o = og * 16 + q * 4 + j;
      const float fv = feat[((size_t)b * 64 + o) * 4096 + n0 + nl];
      out[((size_t)b * 64 + o) * 4096 + n0 + nl] = fmaxf((acc[q * 4 + j] + cbv[j]) + fv, 0.f);
    }
  }
}

// ---------------- K6: fuse = relu(f2 @ relu(f1 @ [weighted;out] + b1) + b2) ----------------
__global__ __launch_bounds__(256) void k6_fuse(const float* __restrict__ weighted,
                                               const float* __restrict__ outp,
                                               const float* __restrict__ f1t,
                                               const float* __restrict__ f1_b,
                                               const float* __restrict__ f2t,
                                               const float* __restrict__ f2_b,
                                               float* __restrict__ fuse) {
  __shared__ __attribute__((aligned(16))) float X[128 * 64];  // X[c][ml]
  __shared__ __attribute__((aligned(16))) float H[128 * 64];  // H[c][ml]
  const int t = threadIdx.x;
  const int m0 = blockIdx.x * 64;
  const int b = m0 / 61440;
  const int ml0 = m0 - b * 61440;
  // stage top half: X[c][ml] = weighted[(m0+ml)*64 + c]
  #pragma unroll
  for (int q = 0; q < 4; ++q) {
    const int idxf = (q * 256 + t) * 4;
    const int ml = idxf >> 6, c = idxf & 63;
    const float4 v = *(const float4*)&weighted[(size_t)m0 * 64 + idxf];
    X[(c + 0) * 64 + ml] = v.x;
    X[(c + 1) * 64 + ml] = v.y;
    X[(c + 2) * 64 + ml] = v.z;
    X[(c + 3) * 64 + ml] = v.w;
  }
  // stage bottom half: X[64+c2][ml] = out[b][c2][n(ml)]
  {
    const int mlt = t & 63;
    const int nt = (ml0 + mlt) / 15;
    const float* ob = outp + (size_t)b * 64 * 4096 + nt;
    const int c2b = t >> 6;  // 0..3
    #pragma unroll
    for (int q = 0; q < 16; ++q) {
      const int c2 = q * 4 + c2b;
      X[(64 + c2) * 64 + mlt] = ob[(size_t)c2 * 4096];
    }
  }
  __syncthreads();
  const int og = t >> 3, cg = t & 7;
  const int o0 = og * 4, col0 = cg * 8;
  float acc[4][8];
  #pragma unroll
  for (int i = 0; i < 4; ++i)
    #pragma unroll
    for (int j = 0; j < 8; ++j) acc[i][j] = 0.f;
  #pragma unroll 4
  for (int c = 0; c < 128; ++c) {
    const float4 w4 = *(const float4*)&f1t[c * 128 + o0];
    const float4 xa = *(const float4*)&X[c * 64 + col0];
    const float4 xb = *(const float4*)&X[c * 64 + col0 + 4];
    const float wv[4] = {w4.x, w4.y, w4.z, w4.w};
    const float xv[8] = {xa.x, xa.y, xa.z, xa.w, xb.x, xb.y, xb.z, xb.w};
    #pragma unroll
    for (int i = 0; i < 4; ++i)
      #pragma unroll
      for (int j = 0; j < 8; ++j)
        acc[i][j] = fmaf(wv[i], xv[j], acc[i][j]);
  }
  {
    const float4 b1 = *(const float4*)&f1_b[o0];
    const float b1v[4] = {b1.x, b1.y, b1.z, b1.w};
    #pragma unroll
    for (int i = 0; i < 4; ++i)
      #pragma unroll
      for (int j = 0; j < 8; ++j)
        H[(o0 + i) * 64 + col0 + j] = fmaxf(acc[i][j] + b1v[i], 0.f);
  }
  __syncthreads();
  #pragma unroll
  for (int i = 0; i < 4; ++i)
    #pragma unroll
    for (int j = 0; j < 8; ++j) acc[i][j] = 0.f;
  #pragma unroll 4
  for (int c = 0; c < 128; ++c) {
    const float4 w4 = *(const float4*)&f2t[c * 128 + o0];
    const float4 xa = *(const float4*)&H[c * 64 + col0];
    const float4 xb = *(const float4*)&H[c * 64 + col0 + 4];
    const float wv[4] = {w4.x, w4.y, w4.z, w4.w};
    const float xv[8] = {xa.x, xa.y, xa.z, xa.w, xb.x, xb.y, xb.z, xb.w};
    #pragma unroll
    for (int i = 0; i < 4; ++i)
      #pragma unroll
      for (int j = 0; j < 8; ++j)
        acc[i][j] = fmaf(wv[i], xv[j], acc[i][j]);
  }
  {
    const float4 b2 = *(const float4*)&f2_b[o0];
    const float b2v[4] = {b2.x, b2.y, b2.z, b2.w};
    float* fp = fuse + (size_t)(b * 128 + o0) * 61440 + ml0 + col0;
    #pragma unroll
    for (int i = 0; i < 4; ++i) {
      #pragma unroll
      for (int j = 0; j < 8; ++j)
        fp[j] = fmaxf(acc[i][j] + b2v[i], 0.f);
      fp += 61440;
    }
  }
}

extern "C" void kernel_launch(void* const* d_in, const int* in_sizes, int n_in,
                              void* d_out, int out_size, void* d_ws, size_t ws_size,
                              hipStream_t stream) {
  const float* pos     = (const float*)d_in[0];
  const float* feat    = (const float*)d_in[1];
  const float* kp_pos  = (const float*)d_in[2];
  const float* cb_w    = (const float*)d_in[3];
  const float* cb_b    = (const float*)d_in[4];
  const float* kpw     = (const float*)d_in[5];
  const float* kp_bias = (const float*)d_in[6];
  const float* ce_w    = (const float*)d_in[7];
  const float* ce_b    = (const float*)d_in[8];
  const float* f1_w    = (const float*)d_in[9];
  const float* f1_b    = (const float*)d_in[10];
  const float* f2_w    = (const float*)d_in[11];
  const float* f2_b    = (const float*)d_in[12];
  float* out = (float*)d_out;
  char* ws = (char*)d_ws;
  int*   idx_ws   = (int*)(ws + OFF_IDX);
  float* feat0    = (float*)(ws + OFF_FEAT0);
  float* weighted = (float*)(ws + OFF_WEIGHTED);
  float* rout0    = (float*)(ws + OFF_ROUT0);
  float* f1t      = (float*)(ws + OFF_F1T);
  float* f2t      = (float*)(ws + OFF_F2T);

  k0_init<<<130, 256, 0, stream>>>(f1_w, f2_w, kp_pos, f1t, f2t, feat0, out + OUT_OFF_KP);
  k1_neigh<<<4096, 256, 0, stream>>>(pos, idx_ws);
  k2_feat0<<<4096, 256, 0, stream>>>(feat, cb_w, cb_b, feat0);
  k3_weighted<<<16384, 64, 0, stream>>>(pos, idx_ws, feat0, kp_pos, weighted);
  k4_kpconv<<<512, 256, 0, stream>>>(weighted, kpw, kp_bias, rout0);
  k5_out<<<256, 256, 0, stream>>>(rout0, ce_w, ce_b, feat, out + OUT_OFF_OUT);
  k6_fuse<<<3840, 256, 0, stream>>>(weighted, out + OUT_OFF_OUT, f1t, f1_b, f2t, f2_b,
                                    out + OUT_OFF_FUSE);
}

// Round 2
// 207.692 us; speedup vs baseline: 1.7002x; 1.7002x over previous
//
#include <hip/hip_runtime.h>
#include <hip/hip_bf16.h>
#include <stdint.h>

#define NPTS 4096
#define NB   4
#define KNN  32
#define NKPT 15

// workspace byte offsets (all 256B-aligned)
#define OFF_IDX      0ULL            // 4*4096*32*4        = 2,097,152
#define OFF_FEAT0    2097152ULL      // 4*4097*64*4        = 4,195,328
#define OFF_WEIGHTED 6292480ULL      // 16384*960*4        = 62,914,560
#define OFF_ROUT0    69207040ULL     // 16384*64*4         = 4,194,304
#define OFF_W1P      73401344ULL     // 32,768 (bf16 fragment-packed f1_w)
#define OFF_W2P      73434112ULL     // 32,768 (end 73,466,880)

// d_out float offsets
#define OUT_OFF_OUT  0
#define OUT_OFF_KP   1048576
#define OUT_OFF_FUSE 1048621

typedef __attribute__((ext_vector_type(8))) short short8v;  // 8 bf16 (4 VGPRs)
typedef __attribute__((ext_vector_type(4))) float f32x4;    // MFMA C/D

__device__ __forceinline__ unsigned short bf16b(float f) {
  __hip_bfloat16 h = __float2bfloat16(f);
  return *(unsigned short*)&h;
}
__device__ __forceinline__ unsigned pkbf(float lo, float hi) {
  return (unsigned)bf16b(lo) | ((unsigned)bf16b(hi) << 16);
}

// ---------------- K0: weight prepack (bf16 A-fragments), shadow row, kp copy ----------------
// w1p/w2p layout: idx = ((ot*4+kc)*64 + lane)*8 + j  holds  W[ot*16+(lane&15)][kc*32+(lane>>4)*8+j]
__global__ __launch_bounds__(256) void k0_init(const float* __restrict__ f1_w,
                                               const float* __restrict__ f2_w,
                                               const float* __restrict__ kp_pos,
                                               unsigned short* __restrict__ w1p,
                                               unsigned short* __restrict__ w2p,
                                               float* __restrict__ feat0,
                                               float* __restrict__ out_kp) {
  int t = blockIdx.x * 256 + threadIdx.x;
  if (t < 32768) {
    const int w = t >> 14;
    const int i = t & 16383;
    const int j = i & 7, l = (i >> 3) & 63, kc = (i >> 9) & 3, ot = i >> 11;
    const int o = ot * 16 + (l & 15);
    const int k = kc * 32 + (l >> 4) * 8 + j;
    const float* src = w ? f2_w : f1_w;
    unsigned short* dst = w ? w2p : w1p;
    dst[i] = bf16b(src[o * 128 + k]);
    return;
  }
  t -= 32768;
  if (t < NB * 64) { int b = t >> 6, d = t & 63; feat0[((size_t)b * (NPTS + 1) + NPTS) * 64 + d] = 0.f; return; }
  t -= NB * 64;
  if (t < 45) out_kp[t] = kp_pos[t];
}

// ---------------- K1: ball query, first-32-by-index, f64 distances ----------------
__global__ __launch_bounds__(256) void k1_neigh(const float* __restrict__ pos,
                                                int* __restrict__ idx_ws) {
  const int w = threadIdx.x >> 6, lane = threadIdx.x & 63;
  const int pt = blockIdx.x * 4 + w;
  const int b = pt >> 12, n = pt & 4095;
  const float* px = pos + (size_t)b * 3 * NPTS;
  const double x0 = (double)px[n], y0 = (double)px[NPTS + n], z0 = (double)px[2 * NPTS + n];
  const double ssrc = x0 * x0 + y0 * y0 + z0 * z0;
  const double RAD = 0.1 * 2.0;
  const double R2 = RAD * RAD;
  int cnt = 0;
  int* op = idx_ws + (size_t)pt * KNN;
  for (int ch = 0; ch < 64; ++ch) {
    const int j = ch * 64 + lane;
    const double xj = (double)px[j], yj = (double)px[NPTS + j], zj = (double)px[2 * NPTS + j];
    const double dot  = x0 * xj + y0 * yj + z0 * zj;
    const double sdst = xj * xj + yj * yj + zj * zj;
    const double sq = -2.0 * dot + ssrc + sdst;
    const bool keep = !(sq > R2);
    const unsigned long long m = __ballot(keep);
    if (keep) {
      const int p = cnt + (int)__popcll(m & ((1ULL << lane) - 1ULL));
      if (p < KNN) op[p] = j;
    }
    cnt += (int)__popcll(m);
    if (cnt >= KNN) break;
  }
  const int s = cnt + lane;
  if (s < KNN) op[s] = NPTS;
}

// ---------------- K2: feat0 = cb_w @ feat + cb_b, stored [B][N+1][64] ----------------
__global__ __launch_bounds__(256) void k2_feat0(const float* __restrict__ feat,
                                                const float* __restrict__ cb_w,
                                                const float* __restrict__ cb_b,
                                                float* __restrict__ feat0) {
  __shared__ float cbt[64 * 65];
  const int t = threadIdx.x;
  #pragma unroll
  for (int q = 0; q < 16; ++q) {
    const int idx = q * 256 + t;
    const int d = idx >> 6, c = idx & 63;
    cbt[c * 65 + d] = cb_w[idx];
  }
  __syncthreads();
  const int ptl = t >> 6, d = t & 63;
  const int pt = blockIdx.x * 4 + ptl;
  const int b = pt >> 12, n = pt & 4095;
  const float* fp = feat + (size_t)b * 64 * NPTS + n;
  float acc = 0.f;
  #pragma unroll
  for (int c = 0; c < 64; ++c) acc = fmaf(cbt[c * 65 + d], fp[(size_t)c * NPTS], acc);
  acc += cb_b[d];
  feat0[((size_t)b * (NPTS + 1) + n) * 64 + d] = acc;
}

// ---------------- K3: gather + kernel-point weights + weighted [16384][15][64] ----------------
__global__ __launch_bounds__(64) void k3_weighted(const float* __restrict__ pos,
                                                  const int* __restrict__ idx_ws,
                                                  const float* __restrict__ feat0,
                                                  const float* __restrict__ kp_pos,
                                                  float* __restrict__ weighted) {
  __shared__ int   nidx[KNN];
  __shared__ float npx[KNN], npy[KNN], npz[KNN];
  __shared__ float kp[48];
  __shared__ float wl[KNN * 16];
  const int lane = threadIdx.x;
  const int pt = blockIdx.x;
  const int b = pt >> 12;
  if (lane < 45) kp[lane] = kp_pos[lane];
  if (lane < KNN) {
    const int ki = idx_ws[(size_t)pt * KNN + lane];
    nidx[lane] = ki;
    const bool v = ki < NPTS;
    const float* px = pos + (size_t)b * 3 * NPTS;
    npx[lane] = v ? px[ki] : 1000000.0f;
    npy[lane] = v ? px[NPTS + ki] : 1000000.0f;
    npz[lane] = v ? px[2 * NPTS + ki] : 1000000.0f;
  }
  __syncthreads();
  #pragma unroll
  for (int r = 0; r < 8; ++r) {
    const int i = r * 64 + lane;
    const int k = i >> 4, p = i & 15;
    float wv = 0.f;
    if (p < 15) {
      const float dx = npx[k] - kp[p];
      const float dy = npy[k] - kp[15 + p];
      const float dz = npz[k] - kp[30 + p];
      const float d2 = dx * dx + dy * dy + dz * dz;
      wv = fmaxf(1.0f - sqrtf(d2) / 1.2f, 0.f);
    }
    wl[i] = wv;
  }
  __syncthreads();
  float acc[16];
  #pragma unroll
  for (int p = 0; p < 16; ++p) acc[p] = 0.f;
  const float* f0 = feat0 + (size_t)b * (NPTS + 1) * 64 + lane;
  for (int k = 0; k < KNN; ++k) {
    const float f = f0[(size_t)nidx[k] * 64];
    #pragma unroll
    for (int q = 0; q < 4; ++q) {
      const float4 w4 = *(const float4*)&wl[k * 16 + q * 4];
      acc[q * 4 + 0] = fmaf(w4.x, f, acc[q * 4 + 0]);
      acc[q * 4 + 1] = fmaf(w4.y, f, acc[q * 4 + 1]);
      acc[q * 4 + 2] = fmaf(w4.z, f, acc[q * 4 + 2]);
      acc[q * 4 + 3] = fmaf(w4.w, f, acc[q * 4 + 3]);
    }
  }
  float* wp = weighted + (size_t)pt * NKPT * 64 + lane;
  #pragma unroll
  for (int p = 0; p < 15; ++p) wp[(size_t)p * 64] = acc[p];
}

// ---------------- K4: rout0 = relu(weighted[16384x960] @ kpw[960x64] + bias) ----------------
__global__ __launch_bounds__(256) void k4_kpconv(const float* __restrict__ weighted,
                                                 const float* __restrict__ kpw,
                                                 const float* __restrict__ kp_bias,
                                                 float* __restrict__ rout0) {
  __shared__ float Ast[64 * 36];
  __shared__ float Bs[64 * 64];
  const int t = threadIdx.x;
  const int m0 = blockIdx.x * 32;
  const int tm = t >> 4, td = t & 15;
  float acc[2][4] = {};
  for (int ch = 0; ch < 15; ++ch) {
    const int k0 = ch * 64;
    __syncthreads();
    {
      const int base = t * 8;
      const int mA = base >> 6;
      const int kA = base & 63;
      #pragma unroll
      for (int q = 0; q < 2; ++q) {
        const float4 v = *(const float4*)&weighted[(size_t)(m0 + mA) * 960 + k0 + kA + q * 4];
        Ast[(kA + q * 4 + 0) * 36 + mA] = v.x;
        Ast[(kA + q * 4 + 1) * 36 + mA] = v.y;
        Ast[(kA + q * 4 + 2) * 36 + mA] = v.z;
        Ast[(kA + q * 4 + 3) * 36 + mA] = v.w;
      }
    }
    #pragma unroll
    for (int q = 0; q < 4; ++q) {
      const int idx = q * 1024 + t * 4;
      const int kk = idx >> 6, d = idx & 63;
      *(float4*)&Bs[kk * 64 + d] = *(const float4*)&kpw[(size_t)(k0 + kk) * 64 + d];
    }
    __syncthreads();
    #pragma unroll 8
    for (int kk = 0; kk < 64; ++kk) {
      const float2 a2 = *(const float2*)&Ast[kk * 36 + tm * 2];
      const float4 b4 = *(const float4*)&Bs[kk * 64 + td * 4];
      acc[0][0] = fmaf(a2.x, b4.x, acc[0][0]);
      acc[0][1] = fmaf(a2.x, b4.y, acc[0][1]);
      acc[0][2] = fmaf(a2.x, b4.z, acc[0][2]);
      acc[0][3] = fmaf(a2.x, b4.w, acc[0][3]);
      acc[1][0] = fmaf(a2.y, b4.x, acc[1][0]);
      acc[1][1] = fmaf(a2.y, b4.y, acc[1][1]);
      acc[1][2] = fmaf(a2.y, b4.z, acc[1][2]);
      acc[1][3] = fmaf(a2.y, b4.w, acc[1][3]);
    }
  }
  const float4 bias = *(const float4*)&kp_bias[td * 4];
  #pragma unroll
  for (int i = 0; i < 2; ++i) {
    const int m = m0 + tm * 2 + i;
    float4 o;
    o.x = fmaxf(acc[i][0] + bias.x, 0.f);
    o.y = fmaxf(acc[i][1] + bias.y, 0.f);
    o.z = fmaxf(acc[i][2] + bias.z, 0.f);
    o.w = fmaxf(acc[i][3] + bias.w, 0.f);
    *(float4*)&rout0[(size_t)m * 64 + td * 4] = o;
  }
}

// ---------------- K5: out = relu(ce_w @ rout0 + ce_b + feat) ----------------
__global__ __launch_bounds__(256) void k5_out(const float* __restrict__ rout0,
                                              const float* __restrict__ ce_w,
                                              const float* __restrict__ ce_b,
                                              const float* __restrict__ feat,
                                              float* __restrict__ out) {
  __shared__ float r0[64 * 65];
  __shared__ float cwt[64 * 64];
  const int t = threadIdx.x;
  const int b = blockIdx.x >> 6;
  const int n0 = (blockIdx.x & 63) * 64;
  #pragma unroll
  for (int q = 0; q < 16; ++q) {
    const int idx = q * 256 + t;
    const int rr = idx >> 6, c = idx & 63;
    r0[rr * 65 + c] = rout0[((size_t)b * 4096 + n0 + rr) * 64 + c];
    cwt[idx] = ce_w[(idx & 63) * 64 + (idx >> 6)];
  }
  __syncthreads();
  const int nl = t & 63, og = t >> 6;
  float acc[16];
  #pragma unroll
  for (int j = 0; j < 16; ++j) acc[j] = 0.f;
  for (int c = 0; c < 64; ++c) {
    const float x = r0[nl * 65 + c];
    #pragma unroll
    for (int q = 0; q < 4; ++q) {
      const float4 w4 = *(const float4*)&cwt[c * 64 + og * 16 + q * 4];
      acc[q * 4 + 0] = fmaf(w4.x, x, acc[q * 4 + 0]);
      acc[q * 4 + 1] = fmaf(w4.y, x, acc[q * 4 + 1]);
      acc[q * 4 + 2] = fmaf(w4.z, x, acc[q * 4 + 2]);
      acc[q * 4 + 3] = fmaf(w4.w, x, acc[q * 4 + 3]);
    }
  }
  #pragma unroll
  for (int q = 0; q < 4; ++q) {
    const float4 cb4 = *(const float4*)&ce_b[og * 16 + q * 4];
    const float cbv[4] = {cb4.x, cb4.y, cb4.z, cb4.w};
    #pragma unroll
    for (int j = 0; j < 4; ++j) {
      const int o = og * 16 + q * 4 + j;
      const float fv = feat[((size_t)b * 64 + o) * 4096 + n0 + nl];
      out[((size_t)b * 64 + o) * 4096 + n0 + nl] = fmaxf((acc[q * 4 + j] + cbv[j]) + fv, 0.f);
    }
  }
}

// ---------------- K6: fuse via bf16 MFMA, two stages, H through LDS ----------------
// Block: 128 outputs x 128 columns; 4 waves, wave w owns columns [w*32, w*32+32).
// XB/HB layout (B-fragments): ushort idx = ((mt*4+kc)*64 + lane)*8 + j holds
//   X[c = kc*32 + (lane>>4)*8 + j][m = mt*16 + (lane&15)].
__global__ __launch_bounds__(256, 2) void k6_fuse(const float* __restrict__ weighted,
                                                  const float* __restrict__ outp,
                                                  const unsigned short* __restrict__ w1p,
                                                  const float* __restrict__ f1_b,
                                                  const unsigned short* __restrict__ w2p,
                                                  const float* __restrict__ f2_b,
                                                  float* __restrict__ fuse) {
  __shared__ __attribute__((aligned(16))) unsigned short XB[16384];  // 32 KB
  __shared__ __attribute__((aligned(16))) unsigned short HB[16384];  // 32 KB
  const int t = threadIdx.x;
  const int blk = blockIdx.x;
  const int b = blk / 480;
  const int ml0 = (blk - b * 480) * 128;
  const size_t M0 = (size_t)blk * 128;

  // stage top half of X (c=0..63) from weighted [m][c]
  #pragma unroll
  for (int q = 0; q < 4; ++q) {
    const int chunk = q * 256 + t;          // (m, a): c = a*8..a*8+7
    const int m = chunk >> 3, a = chunk & 7;
    const float4 v0 = *(const float4*)&weighted[(M0 + m) * 64 + a * 8];
    const float4 v1 = *(const float4*)&weighted[(M0 + m) * 64 + a * 8 + 4];
    const int kc = a >> 2, hi = a & 3;
    const int ln = hi * 16 + (m & 15);
    uint4 pk;
    pk.x = pkbf(v0.x, v0.y); pk.y = pkbf(v0.z, v0.w);
    pk.z = pkbf(v1.x, v1.y); pk.w = pkbf(v1.z, v1.w);
    *(uint4*)&XB[(((m >> 4) * 4 + kc) * 64 + ln) * 8] = pk;
  }
  // stage bottom half of X (c=64..127) from out[b][c2][n], n = (ml0+m)/15
  #pragma unroll
  for (int q = 0; q < 4; ++q) {
    const int chunk = q * 256 + t;
    const int m = chunk >> 3, a = chunk & 7;
    const int n = (ml0 + m) / 15;
    const float* op = outp + ((size_t)b * 64 + a * 8) * 4096 + n;
    float v[8];
    #pragma unroll
    for (int i = 0; i < 8; ++i) v[i] = op[(size_t)i * 4096];
    const int c0 = 64 + a * 8;
    const int kc = c0 >> 5, hi = (c0 >> 3) & 3;
    const int ln = hi * 16 + (m & 15);
    uint4 pk;
    pk.x = pkbf(v[0], v[1]); pk.y = pkbf(v[2], v[3]);
    pk.z = pkbf(v[4], v[5]); pk.w = pkbf(v[6], v[7]);
    *(uint4*)&XB[(((m >> 4) * 4 + kc) * 64 + ln) * 8] = pk;
  }
  __syncthreads();

  const int wv = t >> 6, lane = t & 63;
  const short8v* w1f = (const short8v*)w1p;
  const short8v* w2f = (const short8v*)w2p;
  f32x4 acc[8][2];
  #pragma unroll
  for (int ot = 0; ot < 8; ++ot) {
    acc[ot][0] = (f32x4){0.f, 0.f, 0.f, 0.f};
    acc[ot][1] = (f32x4){0.f, 0.f, 0.f, 0.f};
  }
  // stage 1: H = relu(W1 @ X + b1)
  #pragma unroll
  for (int kc = 0; kc < 4; ++kc) {
    const short8v bf0 = *(const short8v*)&XB[(((wv * 2 + 0) * 4 + kc) * 64 + lane) * 8];
    const short8v bf1 = *(const short8v*)&XB[(((wv * 2 + 1) * 4 + kc) * 64 + lane) * 8];
    #pragma unroll
    for (int ot = 0; ot < 8; ++ot) {
      const short8v af = w1f[(ot * 4 + kc) * 64 + lane];
      acc[ot][0] = __builtin_amdgcn_mfma_f32_16x16x32_bf16(af, bf0, acc[ot][0], 0, 0, 0);
      acc[ot][1] = __builtin_amdgcn_mfma_f32_16x16x32_bf16(af, bf1, acc[ot][1], 0, 0, 0);
    }
  }
  // H epilogue -> HB (per-wave-private region; no barrier needed)
  const int rb = (lane >> 4) * 4;
  #pragma unroll
  for (int ot = 0; ot < 8; ++ot) {
    const int o0 = ot * 16 + rb;
    const float4 b1 = *(const float4*)&f1_b[o0];
    const int kc = o0 >> 5, hi = (o0 >> 3) & 3, j0 = o0 & 7;
    #pragma unroll
    for (int mt = 0; mt < 2; ++mt) {
      const f32x4 h = acc[ot][mt];
      const float h0 = fmaxf(h[0] + b1.x, 0.f);
      const float h1 = fmaxf(h[1] + b1.y, 0.f);
      const float h2 = fmaxf(h[2] + b1.z, 0.f);
      const float h3 = fmaxf(h[3] + b1.w, 0.f);
      uint2 pk;
      pk.x = pkbf(h0, h1);
      pk.y = pkbf(h2, h3);
      *(uint2*)&HB[(((wv * 2 + mt) * 4 + kc) * 64 + hi * 16 + (lane & 15)) * 8 + j0] = pk;
    }
  }
  // stage 2: F = relu(W2 @ H + b2)
  #pragma unroll
  for (int ot = 0; ot < 8; ++ot) {
    acc[ot][0] = (f32x4){0.f, 0.f, 0.f, 0.f};
    acc[ot][1] = (f32x4){0.f, 0.f, 0.f, 0.f};
  }
  #pragma unroll
  for (int kc = 0; kc < 4; ++kc) {
    const short8v bf0 = *(const short8v*)&HB[(((wv * 2 + 0) * 4 + kc) * 64 + lane) * 8];
    const short8v bf1 = *(const short8v*)&HB[(((wv * 2 + 1) * 4 + kc) * 64 + lane) * 8];
    #pragma unroll
    for (int ot = 0; ot < 8; ++ot) {
      const short8v af = w2f[(ot * 4 + kc) * 64 + lane];
      acc[ot][0] = __builtin_amdgcn_mfma_f32_16x16x32_bf16(af, bf0, acc[ot][0], 0, 0, 0);
      acc[ot][1] = __builtin_amdgcn_mfma_f32_16x16x32_bf16(af, bf1, acc[ot][1], 0, 0, 0);
    }
  }
  // F epilogue -> global
  float* fp0 = fuse + (size_t)b * 128 * 61440 + ml0 + wv * 32 + (lane & 15);
  #pragma unroll
  for (int ot = 0; ot < 8; ++ot) {
    const int o0 = ot * 16 + rb;
    const float4 b2 = *(const float4*)&f2_b[o0];
    const float bv[4] = {b2.x, b2.y, b2.z, b2.w};
    #pragma unroll
    for (int mt = 0; mt < 2; ++mt) {
      const f32x4 vacc = acc[ot][mt];
      #pragma unroll
      for (int r = 0; r < 4; ++r)
        fp0[(size_t)(o0 + r) * 61440 + mt * 16] = fmaxf(vacc[r] + bv[r], 0.f);
    }
  }
}

extern "C" void kernel_launch(void* const* d_in, const int* in_sizes, int n_in,
                              void* d_out, int out_size, void* d_ws, size_t ws_size,
                              hipStream_t stream) {
  const float* pos     = (const float*)d_in[0];
  const float* feat    = (const float*)d_in[1];
  const float* kp_pos  = (const float*)d_in[2];
  const float* cb_w    = (const float*)d_in[3];
  const float* cb_b    = (const float*)d_in[4];
  const float* kpw     = (const float*)d_in[5];
  const float* kp_bias = (const float*)d_in[6];
  const float* ce_w    = (const float*)d_in[7];
  const float* ce_b    = (const float*)d_in[8];
  const float* f1_w    = (const float*)d_in[9];
  const float* f1_b    = (const float*)d_in[10];
  const float* f2_w    = (const float*)d_in[11];
  const float* f2_b    = (const float*)d_in[12];
  float* out = (float*)d_out;
  char* ws = (char*)d_ws;
  int*   idx_ws   = (int*)(ws + OFF_IDX);
  float* feat0    = (float*)(ws + OFF_FEAT0);
  float* weighted = (float*)(ws + OFF_WEIGHTED);
  float* rout0    = (float*)(ws + OFF_ROUT0);
  unsigned short* w1p = (unsigned short*)(ws + OFF_W1P);
  unsigned short* w2p = (unsigned short*)(ws + OFF_W2P);

  k0_init<<<130, 256, 0, stream>>>(f1_w, f2_w, kp_pos, w1p, w2p, feat0, out + OUT_OFF_KP);
  k1_neigh<<<4096, 256, 0, stream>>>(pos, idx_ws);
  k2_feat0<<<4096, 256, 0, stream>>>(feat, cb_w, cb_b, feat0);
  k3_weighted<<<16384, 64, 0, stream>>>(pos, idx_ws, feat0, kp_pos, weighted);
  k4_kpconv<<<512, 256, 0, stream>>>(weighted, kpw, kp_bias, rout0);
  k5_out<<<256, 256, 0, stream>>>(rout0, ce_w, ce_b, feat, out + OUT_OFF_OUT);
  k6_fuse<<<1920, 256, 0, stream>>>(weighted, out + OUT_OFF_OUT, w1p, f1_b, w2p, f2_b,
                                    out + OUT_OFF_FUSE);
}

// Round 3
// 184.457 us; speedup vs baseline: 1.9143x; 1.1260x over previous
//
#include <hip/hip_runtime.h>
#include <hip/hip_bf16.h>
#include <stdint.h>

#define NPTS 4096
#define NB   4
#define KNN  32
#define NKPT 15

// workspace byte offsets (all 256B-aligned)
#define OFF_IDX      0ULL            // 4*4096*32*4          = 2,097,152
#define OFF_FEAT0    2097152ULL      // 4*4097*64*4          = 4,195,328
#define OFF_WEIGHTED 6292480ULL      // 16384*960*2 (bf16)   = 31,457,280
#define OFF_ROUT0    37749760ULL     // 16384*64*4           = 4,194,304
#define OFF_W1P      41944064ULL     // 32,768
#define OFF_W2P      41976832ULL     // 32,768
#define OFF_KPWP     42009600ULL     // 960*64*2 = 122,880 (end 42,132,480)

// d_out float offsets
#define OUT_OFF_OUT  0
#define OUT_OFF_KP   1048576
#define OUT_OFF_FUSE 1048621

// LDS unit-index XOR swizzle (16B units): breaks staging-store bank collisions,
// read side stays a permutation within each 8-unit (128B) group.
#define SBU(u) ((u) ^ (((u) >> 3) & 7))

typedef __attribute__((ext_vector_type(8))) short short8v;  // 8 bf16 (4 VGPRs)
typedef __attribute__((ext_vector_type(4))) float f32x4;    // MFMA C/D

__device__ __forceinline__ unsigned short bf16b(float f) {
  __hip_bfloat16 h = __float2bfloat16(f);
  return *(unsigned short*)&h;
}
__device__ __forceinline__ unsigned pkbf(float lo, float hi) {
  return (unsigned)bf16b(lo) | ((unsigned)bf16b(hi) << 16);
}

// ---------------- K0: weight prepacks (bf16 fragments), shadow row, kp copy ----------------
// w1p/w2p (A-frags): idx = ((ot*4+kc)*64 + l)*8 + j -> W[ot*16+(l&15)][kc*32+(l>>4)*8+j]
// kpwp (B-frags):    idx = ((kc*4+nt)*64 + l)*8 + j -> kpw[kc*32+(l>>4)*8+j][nt*16+(l&15)]
__global__ __launch_bounds__(256) void k0_init(const float* __restrict__ f1_w,
                                               const float* __restrict__ f2_w,
                                               const float* __restrict__ kpw,
                                               const float* __restrict__ kp_pos,
                                               unsigned short* __restrict__ w1p,
                                               unsigned short* __restrict__ w2p,
                                               unsigned short* __restrict__ kpwp,
                                               float* __restrict__ feat0,
                                               float* __restrict__ out_kp) {
  int t = blockIdx.x * 256 + threadIdx.x;
  if (t < 32768) {
    const int w = t >> 14;
    const int i = t & 16383;
    const int j = i & 7, l = (i >> 3) & 63, kc = (i >> 9) & 3, ot = i >> 11;
    const int o = ot * 16 + (l & 15);
    const int k = kc * 32 + (l >> 4) * 8 + j;
    const float* src = w ? f2_w : f1_w;
    unsigned short* dst = w ? w2p : w1p;
    dst[i] = bf16b(src[o * 128 + k]);
    return;
  }
  t -= 32768;
  if (t < 61440) {
    const int j = t & 7, l = (t >> 3) & 63, nt = (t >> 9) & 3, kc = t >> 11;  // kc 0..29
    const int k = kc * 32 + (l >> 4) * 8 + j;
    const int d = nt * 16 + (l & 15);
    kpwp[t] = bf16b(kpw[(size_t)k * 64 + d]);
    return;
  }
  t -= 61440;
  if (t < NB * 64) { int b = t >> 6, d = t & 63; feat0[((size_t)b * (NPTS + 1) + NPTS) * 64 + d] = 0.f; return; }
  t -= NB * 64;
  if (t < 45) out_kp[t] = kp_pos[t];
}

// ---------------- K1: ball query, first-32-by-index, f64 distances ----------------
__global__ __launch_bounds__(256) void k1_neigh(const float* __restrict__ pos,
                                                int* __restrict__ idx_ws) {
  const int w = threadIdx.x >> 6, lane = threadIdx.x & 63;
  const int pt = blockIdx.x * 4 + w;
  const int b = pt >> 12, n = pt & 4095;
  const float* px = pos + (size_t)b * 3 * NPTS;
  const double x0 = (double)px[n], y0 = (double)px[NPTS + n], z0 = (double)px[2 * NPTS + n];
  const double ssrc = x0 * x0 + y0 * y0 + z0 * z0;
  const double RAD = 0.1 * 2.0;
  const double R2 = RAD * RAD;
  int cnt = 0;
  int* op = idx_ws + (size_t)pt * KNN;
  for (int ch = 0; ch < 64; ++ch) {
    const int j = ch * 64 + lane;
    const double xj = (double)px[j], yj = (double)px[NPTS + j], zj = (double)px[2 * NPTS + j];
    const double dot  = x0 * xj + y0 * yj + z0 * zj;
    const double sdst = xj * xj + yj * yj + zj * zj;
    const double sq = -2.0 * dot + ssrc + sdst;
    const bool keep = !(sq > R2);
    const unsigned long long m = __ballot(keep);
    if (keep) {
      const int p = cnt + (int)__popcll(m & ((1ULL << lane) - 1ULL));
      if (p < KNN) op[p] = j;
    }
    cnt += (int)__popcll(m);
    if (cnt >= KNN) break;
  }
  const int s = cnt + lane;
  if (s < KNN) op[s] = NPTS;
}

// ---------------- K2: feat0 = cb_w @ feat + cb_b, stored [B][N+1][64] ----------------
__global__ __launch_bounds__(256) void k2_feat0(const float* __restrict__ feat,
                                                const float* __restrict__ cb_w,
                                                const float* __restrict__ cb_b,
                                                float* __restrict__ feat0) {
  __shared__ float cbt[64 * 65];
  const int t = threadIdx.x;
  #pragma unroll
  for (int q = 0; q < 16; ++q) {
    const int idx = q * 256 + t;
    const int d = idx >> 6, c = idx & 63;
    cbt[c * 65 + d] = cb_w[idx];
  }
  __syncthreads();
  const int ptl = t >> 6, d = t & 63;
  const int pt = blockIdx.x * 4 + ptl;
  const int b = pt >> 12, n = pt & 4095;
  const float* fp = feat + (size_t)b * 64 * NPTS + n;
  float acc = 0.f;
  #pragma unroll
  for (int c = 0; c < 64; ++c) acc = fmaf(cbt[c * 65 + d], fp[(size_t)c * NPTS], acc);
  acc += cb_b[d];
  feat0[((size_t)b * (NPTS + 1) + n) * 64 + d] = acc;
}

// ---------------- K3: gather + kernel-point weights + weighted bf16 [16384][960] ----------------
__global__ __launch_bounds__(64) void k3_weighted(const float* __restrict__ pos,
                                                  const int* __restrict__ idx_ws,
                                                  const float* __restrict__ feat0,
                                                  const float* __restrict__ kp_pos,
                                                  unsigned short* __restrict__ wbf) {
  __shared__ int   nidx[KNN];
  __shared__ float npx[KNN], npy[KNN], npz[KNN];
  __shared__ float kp[48];
  __shared__ float wl[KNN * 16];
  const int lane = threadIdx.x;
  const int pt = blockIdx.x;
  const int b = pt >> 12;
  if (lane < 45) kp[lane] = kp_pos[lane];
  if (lane < KNN) {
    const int ki = idx_ws[(size_t)pt * KNN + lane];
    nidx[lane] = ki;
    const bool v = ki < NPTS;
    const float* px = pos + (size_t)b * 3 * NPTS;
    npx[lane] = v ? px[ki] : 1000000.0f;
    npy[lane] = v ? px[NPTS + ki] : 1000000.0f;
    npz[lane] = v ? px[2 * NPTS + ki] : 1000000.0f;
  }
  __syncthreads();
  #pragma unroll
  for (int r = 0; r < 8; ++r) {
    const int i = r * 64 + lane;
    const int k = i >> 4, p = i & 15;
    float wv = 0.f;
    if (p < 15) {
      const float dx = npx[k] - kp[p];
      const float dy = npy[k] - kp[15 + p];
      const float dz = npz[k] - kp[30 + p];
      const float d2 = dx * dx + dy * dy + dz * dz;
      wv = fmaxf(1.0f - sqrtf(d2) / 1.2f, 0.f);
    }
    wl[i] = wv;
  }
  __syncthreads();
  float acc[16];
  #pragma unroll
  for (int p = 0; p < 16; ++p) acc[p] = 0.f;
  const float* f0 = feat0 + (size_t)b * (NPTS + 1) * 64 + lane;
  for (int k = 0; k < KNN; ++k) {
    const float f = f0[(size_t)nidx[k] * 64];
    #pragma unroll
    for (int q = 0; q < 4; ++q) {
      const float4 w4 = *(const float4*)&wl[k * 16 + q * 4];
      acc[q * 4 + 0] = fmaf(w4.x, f, acc[q * 4 + 0]);
      acc[q * 4 + 1] = fmaf(w4.y, f, acc[q * 4 + 1]);
      acc[q * 4 + 2] = fmaf(w4.z, f, acc[q * 4 + 2]);
      acc[q * 4 + 3] = fmaf(w4.w, f, acc[q * 4 + 3]);
    }
  }
  unsigned short* wp = wbf + (size_t)pt * NKPT * 64 + lane;
  #pragma unroll
  for (int p = 0; p < 15; ++p) wp[(size_t)p * 64] = bf16b(acc[p]);
}

// ---------------- K4: rout0 = relu(weighted[16384x960]bf16 @ kpw[960x64]bf16 + bias), MFMA ----------------
__global__ __launch_bounds__(64) void k4_kpconv(const unsigned short* __restrict__ wbf,
                                                const unsigned short* __restrict__ kpwp,
                                                const float* __restrict__ kp_bias,
                                                float* __restrict__ rout0) {
  const int lane = threadIdx.x;
  const int m0 = blockIdx.x * 16;
  const short8v* kf = (const short8v*)kpwp;
  f32x4 acc[4];
  #pragma unroll
  for (int nt = 0; nt < 4; ++nt) acc[nt] = (f32x4){0.f, 0.f, 0.f, 0.f};
  const unsigned short* ap = wbf + (size_t)(m0 + (lane & 15)) * 960 + (lane >> 4) * 8;
  #pragma unroll 6
  for (int kc = 0; kc < 30; ++kc) {
    const short8v a = *(const short8v*)&ap[kc * 32];
    #pragma unroll
    for (int nt = 0; nt < 4; ++nt)
      acc[nt] = __builtin_amdgcn_mfma_f32_16x16x32_bf16(a, kf[(kc * 4 + nt) * 64 + lane], acc[nt], 0, 0, 0);
  }
  const int row = m0 + (lane >> 4) * 4;
  #pragma unroll
  for (int nt = 0; nt < 4; ++nt) {
    const int d = nt * 16 + (lane & 15);
    const float bv = kp_bias[d];
    #pragma unroll
    for (int r = 0; r < 4; ++r)
      rout0[(size_t)(row + r) * 64 + d] = fmaxf(acc[nt][r] + bv, 0.f);
  }
}

// ---------------- K5: out = relu(ce_w @ rout0 + ce_b + feat) ----------------
__global__ __launch_bounds__(256) void k5_out(const float* __restrict__ rout0,
                                              const float* __restrict__ ce_w,
                                              const float* __restrict__ ce_b,
                                              const float* __restrict__ feat,
                                              float* __restrict__ out) {
  __shared__ float r0[64 * 65];
  __shared__ float cwt[64 * 64];
  const int t = threadIdx.x;
  const int b = blockIdx.x >> 6;
  const int n0 = (blockIdx.x & 63) * 64;
  #pragma unroll
  for (int q = 0; q < 16; ++q) {
    const int idx = q * 256 + t;
    const int rr = idx >> 6, c = idx & 63;
    r0[rr * 65 + c] = rout0[((size_t)b * 4096 + n0 + rr) * 64 + c];
    cwt[idx] = ce_w[(idx & 63) * 64 + (idx >> 6)];
  }
  __syncthreads();
  const int nl = t & 63, og = t >> 6;
  float acc[16];
  #pragma unroll
  for (int j = 0; j < 16; ++j) acc[j] = 0.f;
  for (int c = 0; c < 64; ++c) {
    const float x = r0[nl * 65 + c];
    #pragma unroll
    for (int q = 0; q < 4; ++q) {
      const float4 w4 = *(const float4*)&cwt[c * 64 + og * 16 + q * 4];
      acc[q * 4 + 0] = fmaf(w4.x, x, acc[q * 4 + 0]);
      acc[q * 4 + 1] = fmaf(w4.y, x, acc[q * 4 + 1]);
      acc[q * 4 + 2] = fmaf(w4.z, x, acc[q * 4 + 2]);
      acc[q * 4 + 3] = fmaf(w4.w, x, acc[q * 4 + 3]);
    }
  }
  #pragma unroll
  for (int q = 0; q < 4; ++q) {
    const float4 cb4 = *(const float4*)&ce_b[og * 16 + q * 4];
    const float cbv[4] = {cb4.x, cb4.y, cb4.z, cb4.w};
    #pragma unroll
    for (int j = 0; j < 4; ++j) {
      const int o = og * 16 + q * 4 + j;
      const float fv = feat[((size_t)b * 64 + o) * 4096 + n0 + nl];
      out[((size_t)b * 64 + o) * 4096 + n0 + nl] = fmaxf((acc[q * 4 + j] + cbv[j]) + fv, 0.f);
    }
  }
}

// ---------------- K6: fuse via bf16 MFMA, 32KB LDS (H aliases X), XOR-swizzled ----------------
// Block: 128 outputs x 128 columns; wave w owns columns [w*32, w*32+32) == SB slots [w*8, w*8+8).
// SB fragment layout (16B units): unit u = slot*64 + ln, slot = mt*4+kc, ln encodes
//   X[c = kc*32 + (ln>>4)*8 + j][m = mt*16 + (ln&15)]; stored at SBU(u).
__global__ __launch_bounds__(256, 3) void k6_fuse(const unsigned short* __restrict__ wbf,
                                                  const float* __restrict__ outp,
                                                  const unsigned short* __restrict__ w1p,
                                                  const float* __restrict__ f1_b,
                                                  const unsigned short* __restrict__ w2p,
                                                  const float* __restrict__ f2_b,
                                                  float* __restrict__ fuse) {
  __shared__ __attribute__((aligned(16))) unsigned short SB[16384];  // 32 KB
  const int t = threadIdx.x;
  const int blk = blockIdx.x;
  const int b = blk / 480;
  const int ml0 = (blk - b * 480) * 128;
  const size_t M0 = (size_t)blk * 128;

  // stage top half of X (c=0..63): pure bf16 bit-copy from weighted
  #pragma unroll
  for (int q = 0; q < 4; ++q) {
    const int chunk = q * 256 + t;
    const int m = chunk >> 3, a = chunk & 7;
    const uint4 pk = *(const uint4*)&wbf[(M0 + m) * 64 + a * 8];
    const int kc = a >> 2, hi = a & 3;
    const int u = ((m >> 4) * 4 + kc) * 64 + hi * 16 + (m & 15);
    *(uint4*)&SB[SBU(u) * 8] = pk;
  }
  // stage bottom half of X (c=64..127) from out[b][c2][n], n = (ml0+m)/15
  #pragma unroll
  for (int q = 0; q < 4; ++q) {
    const int chunk = q * 256 + t;
    const int m = chunk >> 3, a = chunk & 7;
    const int n = (ml0 + m) / 15;
    const float* op = outp + ((size_t)b * 64 + a * 8) * 4096 + n;
    float v[8];
    #pragma unroll
    for (int i = 0; i < 8; ++i) v[i] = op[(size_t)i * 4096];
    const int c0 = 64 + a * 8;
    const int kc = c0 >> 5, hi = (c0 >> 3) & 3;
    const int u = ((m >> 4) * 4 + kc) * 64 + hi * 16 + (m & 15);
    uint4 pk;
    pk.x = pkbf(v[0], v[1]); pk.y = pkbf(v[2], v[3]);
    pk.z = pkbf(v[4], v[5]); pk.w = pkbf(v[6], v[7]);
    *(uint4*)&SB[SBU(u) * 8] = pk;
  }
  __syncthreads();

  const int wv = t >> 6, lane = t & 63;
  const short8v* w1f = (const short8v*)w1p;
  const short8v* w2f = (const short8v*)w2p;

  // hoist this wave's 8 X B-fragments (frees the wave's SB region for H)
  short8v xf[8];
  #pragma unroll
  for (int mt = 0; mt < 2; ++mt)
    #pragma unroll
    for (int kc = 0; kc < 4; ++kc) {
      const int u = ((wv * 2 + mt) * 4 + kc) * 64 + lane;
      xf[mt * 4 + kc] = *(const short8v*)&SB[SBU(u) * 8];
    }

  f32x4 acc[8][2];
  #pragma unroll
  for (int ot = 0; ot < 8; ++ot) {
    acc[ot][0] = (f32x4){0.f, 0.f, 0.f, 0.f};
    acc[ot][1] = (f32x4){0.f, 0.f, 0.f, 0.f};
  }
  // stage 1: H = relu(W1 @ X + b1)
  #pragma unroll
  for (int kc = 0; kc < 4; ++kc) {
    #pragma unroll
    for (int ot = 0; ot < 8; ++ot) {
      const short8v af = w1f[(ot * 4 + kc) * 64 + lane];
      acc[ot][0] = __builtin_amdgcn_mfma_f32_16x16x32_bf16(af, xf[kc],     acc[ot][0], 0, 0, 0);
      acc[ot][1] = __builtin_amdgcn_mfma_f32_16x16x32_bf16(af, xf[4 + kc], acc[ot][1], 0, 0, 0);
    }
  }
  // H epilogue -> wave's own SB region (per-wave private; same-wave DS ordering)
  const int rb = (lane >> 4) * 4;
  #pragma unroll
  for (int ot = 0; ot < 8; ++ot) {
    const int o0 = ot * 16 + rb;
    const float4 b1 = *(const float4*)&f1_b[o0];
    const int kc = o0 >> 5, hi = (o0 >> 3) & 3, j0 = o0 & 7;
    #pragma unroll
    for (int mt = 0; mt < 2; ++mt) {
      const f32x4 h = acc[ot][mt];
      const float h0 = fmaxf(h[0] + b1.x, 0.f);
      const float h1 = fmaxf(h[1] + b1.y, 0.f);
      const float h2 = fmaxf(h[2] + b1.z, 0.f);
      const float h3 = fmaxf(h[3] + b1.w, 0.f);
      const int u = ((wv * 2 + mt) * 4 + kc) * 64 + hi * 16 + (lane & 15);
      uint2 pk;
      pk.x = pkbf(h0, h1);
      pk.y = pkbf(h2, h3);
      *(uint2*)&SB[SBU(u) * 8 + j0] = pk;
    }
  }
  // stage 2: F = relu(W2 @ H + b2)
  #pragma unroll
  for (int ot = 0; ot < 8; ++ot) {
    acc[ot][0] = (f32x4){0.f, 0.f, 0.f, 0.f};
    acc[ot][1] = (f32x4){0.f, 0.f, 0.f, 0.f};
  }
  #pragma unroll
  for (int kc = 0; kc < 4; ++kc) {
    const int u0 = ((wv * 2 + 0) * 4 + kc) * 64 + lane;
    const int u1 = ((wv * 2 + 1) * 4 + kc) * 64 + lane;
    const short8v bf0 = *(const short8v*)&SB[SBU(u0) * 8];
    const short8v bf1 = *(const short8v*)&SB[SBU(u1) * 8];
    #pragma unroll
    for (int ot = 0; ot < 8; ++ot) {
      const short8v af = w2f[(ot * 4 + kc) * 64 + lane];
      acc[ot][0] = __builtin_amdgcn_mfma_f32_16x16x32_bf16(af, bf0, acc[ot][0], 0, 0, 0);
      acc[ot][1] = __builtin_amdgcn_mfma_f32_16x16x32_bf16(af, bf1, acc[ot][1], 0, 0, 0);
    }
  }
  // F epilogue -> global
  float* fp0 = fuse + (size_t)b * 128 * 61440 + ml0 + wv * 32 + (lane & 15);
  #pragma unroll
  for (int ot = 0; ot < 8; ++ot) {
    const int o0 = ot * 16 + rb;
    const float4 b2 = *(const float4*)&f2_b[o0];
    const float bv[4] = {b2.x, b2.y, b2.z, b2.w};
    #pragma unroll
    for (int mt = 0; mt < 2; ++mt) {
      const f32x4 vacc = acc[ot][mt];
      #pragma unroll
      for (int r = 0; r < 4; ++r)
        fp0[(size_t)(o0 + r) * 61440 + mt * 16] = fmaxf(vacc[r] + bv[r], 0.f);
    }
  }
}

extern "C" void kernel_launch(void* const* d_in, const int* in_sizes, int n_in,
                              void* d_out, int out_size, void* d_ws, size_t ws_size,
                              hipStream_t stream) {
  const float* pos     = (const float*)d_in[0];
  const float* feat    = (const float*)d_in[1];
  const float* kp_pos  = (const float*)d_in[2];
  const float* cb_w    = (const float*)d_in[3];
  const float* cb_b    = (const float*)d_in[4];
  const float* kpw     = (const float*)d_in[5];
  const float* kp_bias = (const float*)d_in[6];
  const float* ce_w    = (const float*)d_in[7];
  const float* ce_b    = (const float*)d_in[8];
  const float* f1_w    = (const float*)d_in[9];
  const float* f1_b    = (const float*)d_in[10];
  const float* f2_w    = (const float*)d_in[11];
  const float* f2_b    = (const float*)d_in[12];
  float* out = (float*)d_out;
  char* ws = (char*)d_ws;
  int*   idx_ws   = (int*)(ws + OFF_IDX);
  float* feat0    = (float*)(ws + OFF_FEAT0);
  unsigned short* wbf  = (unsigned short*)(ws + OFF_WEIGHTED);
  float* rout0    = (float*)(ws + OFF_ROUT0);
  unsigned short* w1p  = (unsigned short*)(ws + OFF_W1P);
  unsigned short* w2p  = (unsigned short*)(ws + OFF_W2P);
  unsigned short* kpwp = (unsigned short*)(ws + OFF_KPWP);

  k0_init<<<370, 256, 0, stream>>>(f1_w, f2_w, kpw, kp_pos, w1p, w2p, kpwp, feat0,
                                   out + OUT_OFF_KP);
  k1_neigh<<<4096, 256, 0, stream>>>(pos, idx_ws);
  k2_feat0<<<4096, 256, 0, stream>>>(feat, cb_w, cb_b, feat0);
  k3_weighted<<<16384, 64, 0, stream>>>(pos, idx_ws, feat0, kp_pos, wbf);
  k4_kpconv<<<1024, 64, 0, stream>>>(wbf, kpwp, kp_bias, rout0);
  k5_out<<<256, 256, 0, stream>>>(rout0, ce_w, ce_b, feat, out + OUT_OFF_OUT);
  k6_fuse<<<1920, 256, 0, stream>>>(wbf, out + OUT_OFF_OUT, w1p, f1_b, w2p, f2_b,
                                    out + OUT_OFF_FUSE);
}

// Round 4
// 156.461 us; speedup vs baseline: 2.2569x; 1.1789x over previous
//
#include <hip/hip_runtime.h>
#include <hip/hip_bf16.h>
#include <stdint.h>

#define NPTS 4096
#define NB   4
#define KNN  32
#define NKPT 15

// workspace byte offsets (all 256B-aligned)
#define OFF_IDX      0ULL            // 4*4096*32*4          = 2,097,152
#define OFF_FEAT0    2097152ULL      // 4*4097*64*4          = 4,195,328
#define OFF_WEIGHTED 6292480ULL      // 16384*960*2 (bf16)   = 31,457,280
#define OFF_ROUT0    37749760ULL     // 16384*64*4           = 4,194,304
#define OFF_W1P      41944064ULL     // 32,768
#define OFF_W2P      41976832ULL     // 32,768
#define OFF_KPWP     42009600ULL     // 960*64*2 = 122,880 (end 42,132,480)

// d_out float offsets
#define OUT_OFF_OUT  0
#define OUT_OFF_KP   1048576
#define OUT_OFF_FUSE 1048621

// LDS unit-index XOR swizzle (16B units): breaks staging-store bank collisions,
// read side stays a permutation within each 8-unit (128B) group.
#define SBU(u) ((u) ^ (((u) >> 3) & 7))

typedef __attribute__((ext_vector_type(8))) short short8v;  // 8 bf16 (4 VGPRs)
typedef __attribute__((ext_vector_type(4))) float f32x4;    // MFMA C/D

__device__ __forceinline__ unsigned short bf16b(float f) {
  __hip_bfloat16 h = __float2bfloat16(f);
  return *(unsigned short*)&h;
}
__device__ __forceinline__ unsigned pkbf(float lo, float hi) {
  return (unsigned)bf16b(lo) | ((unsigned)bf16b(hi) << 16);
}

// ---------------- K0: weight prepacks (bf16 fragments), shadow row, kp copy ----------------
// w1p/w2p (A-frags): idx = ((ot*4+kc)*64 + l)*8 + j -> W[ot*16+(l&15)][kc*32+(l>>4)*8+j]
// kpwp (B-frags):    idx = ((kc*4+nt)*64 + l)*8 + j -> kpw[kc*32+(l>>4)*8+j][nt*16+(l&15)]
__global__ __launch_bounds__(256) void k0_init(const float* __restrict__ f1_w,
                                               const float* __restrict__ f2_w,
                                               const float* __restrict__ kpw,
                                               const float* __restrict__ kp_pos,
                                               unsigned short* __restrict__ w1p,
                                               unsigned short* __restrict__ w2p,
                                               unsigned short* __restrict__ kpwp,
                                               float* __restrict__ feat0,
                                               float* __restrict__ out_kp) {
  int t = blockIdx.x * 256 + threadIdx.x;
  if (t < 32768) {
    const int w = t >> 14;
    const int i = t & 16383;
    const int j = i & 7, l = (i >> 3) & 63, kc = (i >> 9) & 3, ot = i >> 11;
    const int o = ot * 16 + (l & 15);
    const int k = kc * 32 + (l >> 4) * 8 + j;
    const float* src = w ? f2_w : f1_w;
    unsigned short* dst = w ? w2p : w1p;
    dst[i] = bf16b(src[o * 128 + k]);
    return;
  }
  t -= 32768;
  if (t < 61440) {
    const int j = t & 7, l = (t >> 3) & 63, nt = (t >> 9) & 3, kc = t >> 11;  // kc 0..29
    const int k = kc * 32 + (l >> 4) * 8 + j;
    const int d = nt * 16 + (l & 15);
    kpwp[t] = bf16b(kpw[(size_t)k * 64 + d]);
    return;
  }
  t -= 61440;
  if (t < NB * 64) { int b = t >> 6, d = t & 63; feat0[((size_t)b * (NPTS + 1) + NPTS) * 64 + d] = 0.f; return; }
  t -= NB * 64;
  if (t < 45) out_kp[t] = kp_pos[t];
}

// ---------------- K1: ball query, first-32-by-index, f64 distances ----------------
__global__ __launch_bounds__(256) void k1_neigh(const float* __restrict__ pos,
                                                int* __restrict__ idx_ws) {
  const int w = threadIdx.x >> 6, lane = threadIdx.x & 63;
  const int pt = blockIdx.x * 4 + w;
  const int b = pt >> 12, n = pt & 4095;
  const float* px = pos + (size_t)b * 3 * NPTS;
  const double x0 = (double)px[n], y0 = (double)px[NPTS + n], z0 = (double)px[2 * NPTS + n];
  const double ssrc = x0 * x0 + y0 * y0 + z0 * z0;
  const double RAD = 0.1 * 2.0;
  const double R2 = RAD * RAD;
  int cnt = 0;
  int* op = idx_ws + (size_t)pt * KNN;
  for (int ch = 0; ch < 64; ++ch) {
    const int j = ch * 64 + lane;
    const double xj = (double)px[j], yj = (double)px[NPTS + j], zj = (double)px[2 * NPTS + j];
    const double dot  = x0 * xj + y0 * yj + z0 * zj;
    const double sdst = xj * xj + yj * yj + zj * zj;
    const double sq = -2.0 * dot + ssrc + sdst;
    const bool keep = !(sq > R2);
    const unsigned long long m = __ballot(keep);
    if (keep) {
      const int p = cnt + (int)__popcll(m & ((1ULL << lane) - 1ULL));
      if (p < KNN) op[p] = j;
    }
    cnt += (int)__popcll(m);
    if (cnt >= KNN) break;
  }
  const int s = cnt + lane;
  if (s < KNN) op[s] = NPTS;
}

// ---------------- K2: feat0 = cb_w @ feat + cb_b, stored [B][N+1][64] ----------------
__global__ __launch_bounds__(256) void k2_feat0(const float* __restrict__ feat,
                                                const float* __restrict__ cb_w,
                                                const float* __restrict__ cb_b,
                                                float* __restrict__ feat0) {
  __shared__ float cbt[64 * 65];
  const int t = threadIdx.x;
  #pragma unroll
  for (int q = 0; q < 16; ++q) {
    const int idx = q * 256 + t;
    const int d = idx >> 6, c = idx & 63;
    cbt[c * 65 + d] = cb_w[idx];
  }
  __syncthreads();
  const int ptl = t >> 6, d = t & 63;
  const int pt = blockIdx.x * 4 + ptl;
  const int b = pt >> 12, n = pt & 4095;
  const float* fp = feat + (size_t)b * 64 * NPTS + n;
  float acc = 0.f;
  #pragma unroll
  for (int c = 0; c < 64; ++c) acc = fmaf(cbt[c * 65 + d], fp[(size_t)c * NPTS], acc);
  acc += cb_b[d];
  feat0[((size_t)b * (NPTS + 1) + n) * 64 + d] = acc;
}

// ---------------- K3: gather + kernel-point weights + weighted bf16 [16384][960] ----------------
__global__ __launch_bounds__(64) void k3_weighted(const float* __restrict__ pos,
                                                  const int* __restrict__ idx_ws,
                                                  const float* __restrict__ feat0,
                                                  const float* __restrict__ kp_pos,
                                                  unsigned short* __restrict__ wbf) {
  __shared__ int   nidx[KNN];
  __shared__ float npx[KNN], npy[KNN], npz[KNN];
  __shared__ float kp[48];
  __shared__ float wl[KNN * 16];
  const int lane = threadIdx.x;
  const int pt = blockIdx.x;
  const int b = pt >> 12;
  if (lane < 45) kp[lane] = kp_pos[lane];
  if (lane < KNN) {
    const int ki = idx_ws[(size_t)pt * KNN + lane];
    nidx[lane] = ki;
    const bool v = ki < NPTS;
    const float* px = pos + (size_t)b * 3 * NPTS;
    npx[lane] = v ? px[ki] : 1000000.0f;
    npy[lane] = v ? px[NPTS + ki] : 1000000.0f;
    npz[lane] = v ? px[2 * NPTS + ki] : 1000000.0f;
  }
  __syncthreads();
  #pragma unroll
  for (int r = 0; r < 8; ++r) {
    const int i = r * 64 + lane;
    const int k = i >> 4, p = i & 15;
    float wv = 0.f;
    if (p < 15) {
      const float dx = npx[k] - kp[p];
      const float dy = npy[k] - kp[15 + p];
      const float dz = npz[k] - kp[30 + p];
      const float d2 = dx * dx + dy * dy + dz * dz;
      wv = fmaxf(1.0f - sqrtf(d2) / 1.2f, 0.f);
    }
    wl[i] = wv;
  }
  __syncthreads();
  float acc[16];
  #pragma unroll
  for (int p = 0; p < 16; ++p) acc[p] = 0.f;
  const float* f0 = feat0 + (size_t)b * (NPTS + 1) * 64 + lane;
  for (int k = 0; k < KNN; ++k) {
    const float f = f0[(size_t)nidx[k] * 64];
    #pragma unroll
    for (int q = 0; q < 4; ++q) {
      const float4 w4 = *(const float4*)&wl[k * 16 + q * 4];
      acc[q * 4 + 0] = fmaf(w4.x, f, acc[q * 4 + 0]);
      acc[q * 4 + 1] = fmaf(w4.y, f, acc[q * 4 + 1]);
      acc[q * 4 + 2] = fmaf(w4.z, f, acc[q * 4 + 2]);
      acc[q * 4 + 3] = fmaf(w4.w, f, acc[q * 4 + 3]);
    }
  }
  unsigned short* wp = wbf + (size_t)pt * NKPT * 64 + lane;
  #pragma unroll
  for (int p = 0; p < 15; ++p) wp[(size_t)p * 64] = bf16b(acc[p]);
}

// ---------------- K4: rout0 = relu(weighted[16384x960]bf16 @ kpw[960x64]bf16 + bias), MFMA ----------------
__global__ __launch_bounds__(64) void k4_kpconv(const unsigned short* __restrict__ wbf,
                                                const unsigned short* __restrict__ kpwp,
                                                const float* __restrict__ kp_bias,
                                                float* __restrict__ rout0) {
  const int lane = threadIdx.x;
  const int m0 = blockIdx.x * 16;
  const short8v* kf = (const short8v*)kpwp;
  f32x4 acc[4];
  #pragma unroll
  for (int nt = 0; nt < 4; ++nt) acc[nt] = (f32x4){0.f, 0.f, 0.f, 0.f};
  const unsigned short* ap = wbf + (size_t)(m0 + (lane & 15)) * 960 + (lane >> 4) * 8;
  #pragma unroll 6
  for (int kc = 0; kc < 30; ++kc) {
    const short8v a = *(const short8v*)&ap[kc * 32];
    #pragma unroll
    for (int nt = 0; nt < 4; ++nt)
      acc[nt] = __builtin_amdgcn_mfma_f32_16x16x32_bf16(a, kf[(kc * 4 + nt) * 64 + lane], acc[nt], 0, 0, 0);
  }
  const int row = m0 + (lane >> 4) * 4;
  #pragma unroll
  for (int nt = 0; nt < 4; ++nt) {
    const int d = nt * 16 + (lane & 15);
    const float bv = kp_bias[d];
    #pragma unroll
    for (int r = 0; r < 4; ++r)
      rout0[(size_t)(row + r) * 64 + d] = fmaxf(acc[nt][r] + bv, 0.f);
  }
}

// ---------------- K5: out = relu(ce_w @ rout0 + ce_b + feat) ----------------
__global__ __launch_bounds__(256) void k5_out(const float* __restrict__ rout0,
                                              const float* __restrict__ ce_w,
                                              const float* __restrict__ ce_b,
                                              const float* __restrict__ feat,
                                              float* __restrict__ out) {
  __shared__ float r0[64 * 65];
  __shared__ float cwt[64 * 64];
  const int t = threadIdx.x;
  const int b = blockIdx.x >> 6;
  const int n0 = (blockIdx.x & 63) * 64;
  #pragma unroll
  for (int q = 0; q < 16; ++q) {
    const int idx = q * 256 + t;
    const int rr = idx >> 6, c = idx & 63;
    r0[rr * 65 + c] = rout0[((size_t)b * 4096 + n0 + rr) * 64 + c];
    cwt[idx] = ce_w[(idx & 63) * 64 + (idx >> 6)];
  }
  __syncthreads();
  const int nl = t & 63, og = t >> 6;
  float acc[16];
  #pragma unroll
  for (int j = 0; j < 16; ++j) acc[j] = 0.f;
  for (int c = 0; c < 64; ++c) {
    const float x = r0[nl * 65 + c];
    #pragma unroll
    for (int q = 0; q < 4; ++q) {
      const float4 w4 = *(const float4*)&cwt[c * 64 + og * 16 + q * 4];
      acc[q * 4 + 0] = fmaf(w4.x, x, acc[q * 4 + 0]);
      acc[q * 4 + 1] = fmaf(w4.y, x, acc[q * 4 + 1]);
      acc[q * 4 + 2] = fmaf(w4.z, x, acc[q * 4 + 2]);
      acc[q * 4 + 3] = fmaf(w4.w, x, acc[q * 4 + 3]);
    }
  }
  #pragma unroll
  for (int q = 0; q < 4; ++q) {
    const float4 cb4 = *(const float4*)&ce_b[og * 16 + q * 4];
    const float cbv[4] = {cb4.x, cb4.y, cb4.z, cb4.w};
    #pragma unroll
    for (int j = 0; j < 4; ++j) {
      const int o = og * 16 + q * 4 + j;
      const float fv = feat[((size_t)b * 64 + o) * 4096 + n0 + nl];
      out[((size_t)b * 64 + o) * 4096 + n0 + nl] = fmaxf((acc[q * 4 + j] + cbv[j]) + fv, 0.f);
    }
  }
}

// ---------------- K6: fuse via bf16 MFMA, register-hoisted weights, LDS out-gather ----------------
// Block: 128 outputs x 128 columns; wave w owns columns [w*32, w*32+32) == SB slots [w*8, w*8+8).
// SB fragment layout (16B units): unit u = slot*64 + ln, slot = mt*4+kc, ln encodes
//   X[c = kc*32 + (ln>>4)*8 + j][m = mt*16 + (ln&15)]; stored at SBU(u).
__global__ __launch_bounds__(256, 2) void k6_fuse(const unsigned short* __restrict__ wbf,
                                                  const float* __restrict__ outp,
                                                  const unsigned short* __restrict__ w1p,
                                                  const float* __restrict__ f1_b,
                                                  const unsigned short* __restrict__ w2p,
                                                  const float* __restrict__ f2_b,
                                                  float* __restrict__ fuse) {
  __shared__ __attribute__((aligned(16))) unsigned short SB[16384];  // 32 KB
  __shared__ float outS[64 * 12];                                    // 3 KB
  const int t = threadIdx.x;
  const int blk = blockIdx.x;
  const int b = blk / 480;
  const int ml0 = (blk - b * 480) * 128;
  const size_t M0 = (size_t)blk * 128;
  const int wv = t >> 6, lane = t & 63;
  const short8v* w1f = (const short8v*)w1p;
  const short8v* w2f = (const short8v*)w2p;

  // early W1 fragment loads — latency hidden under staging + barrier
  short8v w1r[32];
  #pragma unroll
  for (int i = 0; i < 32; ++i) w1r[i] = w1f[i * 64 + lane];

  // cooperative gather: out rows for this tile's n-range (<=10 distinct n)
  const int nmin = ml0 / 15;
  #pragma unroll
  for (int q = 0; q < 3; ++q) {
    const int i = q * 256 + t;  // i < 768
    const int c2 = i / 12, nn = i - c2 * 12;
    int n = nmin + nn;
    if (n > 4095) n = 4095;
    outS[i] = outp[((size_t)b * 64 + c2) * 4096 + n];
  }
  // stage top half of X (c=0..63): pure bf16 bit-copy from weighted
  #pragma unroll
  for (int q = 0; q < 4; ++q) {
    const int chunk = q * 256 + t;
    const int m = chunk >> 3, a = chunk & 7;
    const uint4 pk = *(const uint4*)&wbf[(M0 + m) * 64 + a * 8];
    const int kc = a >> 2, hi = a & 3;
    const int u = ((m >> 4) * 4 + kc) * 64 + hi * 16 + (m & 15);
    *(uint4*)&SB[SBU(u) * 8] = pk;
  }
  __syncthreads();
  // stage bottom half of X (c=64..127) from the LDS out-gather
  #pragma unroll
  for (int q = 0; q < 4; ++q) {
    const int chunk = q * 256 + t;
    const int m = chunk >> 3, a = chunk & 7;
    const int dn = (ml0 + m) / 15 - nmin;
    float v[8];
    #pragma unroll
    for (int i = 0; i < 8; ++i) v[i] = outS[(a * 8 + i) * 12 + dn];
    const int c0 = 64 + a * 8;
    const int kc = c0 >> 5, hi = (c0 >> 3) & 3;
    const int u = ((m >> 4) * 4 + kc) * 64 + hi * 16 + (m & 15);
    uint4 pk;
    pk.x = pkbf(v[0], v[1]); pk.y = pkbf(v[2], v[3]);
    pk.z = pkbf(v[4], v[5]); pk.w = pkbf(v[6], v[7]);
    *(uint4*)&SB[SBU(u) * 8] = pk;
  }
  __syncthreads();

  // hoist this wave's 8 X B-fragments
  short8v xf[8];
  #pragma unroll
  for (int mt = 0; mt < 2; ++mt)
    #pragma unroll
    for (int kc = 0; kc < 4; ++kc) {
      const int u = ((wv * 2 + mt) * 4 + kc) * 64 + lane;
      xf[mt * 4 + kc] = *(const short8v*)&SB[SBU(u) * 8];
    }

  f32x4 acc[8][2];
  #pragma unroll
  for (int ot = 0; ot < 8; ++ot) {
    acc[ot][0] = (f32x4){0.f, 0.f, 0.f, 0.f};
    acc[ot][1] = (f32x4){0.f, 0.f, 0.f, 0.f};
  }
  // stage 1: pure-register MFMA burst
  #pragma unroll
  for (int kc = 0; kc < 4; ++kc) {
    #pragma unroll
    for (int ot = 0; ot < 8; ++ot) {
      acc[ot][0] = __builtin_amdgcn_mfma_f32_16x16x32_bf16(w1r[ot * 4 + kc], xf[kc],     acc[ot][0], 0, 0, 0);
      acc[ot][1] = __builtin_amdgcn_mfma_f32_16x16x32_bf16(w1r[ot * 4 + kc], xf[4 + kc], acc[ot][1], 0, 0, 0);
    }
  }
  // issue W2 loads now — latency covered by H epilogue VALU
  short8v w2r[32];
  #pragma unroll
  for (int i = 0; i < 32; ++i) w2r[i] = w2f[i * 64 + lane];

  // H epilogue -> wave's own SB region (per-wave private; same-wave DS ordering)
  const int rb = (lane >> 4) * 4;
  #pragma unroll
  for (int ot = 0; ot < 8; ++ot) {
    const int o0 = ot * 16 + rb;
    const float4 b1 = *(const float4*)&f1_b[o0];
    const int kc = o0 >> 5, hi = (o0 >> 3) & 3, j0 = o0 & 7;
    #pragma unroll
    for (int mt = 0; mt < 2; ++mt) {
      const f32x4 h = acc[ot][mt];
      const float h0 = fmaxf(h[0] + b1.x, 0.f);
      const float h1 = fmaxf(h[1] + b1.y, 0.f);
      const float h2 = fmaxf(h[2] + b1.z, 0.f);
      const float h3 = fmaxf(h[3] + b1.w, 0.f);
      const int u = ((wv * 2 + mt) * 4 + kc) * 64 + hi * 16 + (lane & 15);
      uint2 pk;
      pk.x = pkbf(h0, h1);
      pk.y = pkbf(h2, h3);
      *(uint2*)&SB[SBU(u) * 8 + j0] = pk;
    }
  }
  // read H fragments
  short8v hf[8];
  #pragma unroll
  for (int mt = 0; mt < 2; ++mt)
    #pragma unroll
    for (int kc = 0; kc < 4; ++kc) {
      const int u = ((wv * 2 + mt) * 4 + kc) * 64 + lane;
      hf[mt * 4 + kc] = *(const short8v*)&SB[SBU(u) * 8];
    }
  // stage 2: pure-register MFMA burst
  #pragma unroll
  for (int ot = 0; ot < 8; ++ot) {
    acc[ot][0] = (f32x4){0.f, 0.f, 0.f, 0.f};
    acc[ot][1] = (f32x4){0.f, 0.f, 0.f, 0.f};
  }
  #pragma unroll
  for (int kc = 0; kc < 4; ++kc) {
    #pragma unroll
    for (int ot = 0; ot < 8; ++ot) {
      acc[ot][0] = __builtin_amdgcn_mfma_f32_16x16x32_bf16(w2r[ot * 4 + kc], hf[kc],     acc[ot][0], 0, 0, 0);
      acc[ot][1] = __builtin_amdgcn_mfma_f32_16x16x32_bf16(w2r[ot * 4 + kc], hf[4 + kc], acc[ot][1], 0, 0, 0);
    }
  }
  // F epilogue -> global
  float* fp0 = fuse + (size_t)b * 128 * 61440 + ml0 + wv * 32 + (lane & 15);
  #pragma unroll
  for (int ot = 0; ot < 8; ++ot) {
    const int o0 = ot * 16 + rb;
    const float4 b2 = *(const float4*)&f2_b[o0];
    const float bv[4] = {b2.x, b2.y, b2.z, b2.w};
    #pragma unroll
    for (int mt = 0; mt < 2; ++mt) {
      const f32x4 vacc = acc[ot][mt];
      #pragma unroll
      for (int r = 0; r < 4; ++r)
        fp0[(size_t)(o0 + r) * 61440 + mt * 16] = fmaxf(vacc[r] + bv[r], 0.f);
    }
  }
}

extern "C" void kernel_launch(void* const* d_in, const int* in_sizes, int n_in,
                              void* d_out, int out_size, void* d_ws, size_t ws_size,
                              hipStream_t stream) {
  const float* pos     = (const float*)d_in[0];
  const float* feat    = (const float*)d_in[1];
  const float* kp_pos  = (const float*)d_in[2];
  const float* cb_w    = (const float*)d_in[3];
  const float* cb_b    = (const float*)d_in[4];
  const float* kpw     = (const float*)d_in[5];
  const float* kp_bias = (const float*)d_in[6];
  const float* ce_w    = (const float*)d_in[7];
  const float* ce_b    = (const float*)d_in[8];
  const float* f1_w    = (const float*)d_in[9];
  const float* f1_b    = (const float*)d_in[10];
  const float* f2_w    = (const float*)d_in[11];
  const float* f2_b    = (const float*)d_in[12];
  float* out = (float*)d_out;
  char* ws = (char*)d_ws;
  int*   idx_ws   = (int*)(ws + OFF_IDX);
  float* feat0    = (float*)(ws + OFF_FEAT0);
  unsigned short* wbf  = (unsigned short*)(ws + OFF_WEIGHTED);
  float* rout0    = (float*)(ws + OFF_ROUT0);
  unsigned short* w1p  = (unsigned short*)(ws + OFF_W1P);
  unsigned short* w2p  = (unsigned short*)(ws + OFF_W2P);
  unsigned short* kpwp = (unsigned short*)(ws + OFF_KPWP);

  k0_init<<<370, 256, 0, stream>>>(f1_w, f2_w, kpw, kp_pos, w1p, w2p, kpwp, feat0,
                                   out + OUT_OFF_KP);
  k1_neigh<<<4096, 256, 0, stream>>>(pos, idx_ws);
  k2_feat0<<<4096, 256, 0, stream>>>(feat, cb_w, cb_b, feat0);
  k3_weighted<<<16384, 64, 0, stream>>>(pos, idx_ws, feat0, kp_pos, wbf);
  k4_kpconv<<<1024, 64, 0, stream>>>(wbf, kpwp, kp_bias, rout0);
  k5_out<<<256, 256, 0, stream>>>(rout0, ce_w, ce_b, feat, out + OUT_OFF_OUT);
  k6_fuse<<<1920, 256, 0, stream>>>(wbf, out + OUT_OFF_OUT, w1p, f1_b, w2p, f2_b,
                                    out + OUT_OFF_FUSE);
}

// Round 5
// 134.180 us; speedup vs baseline: 2.6316x; 1.1661x over previous
//
#include <hip/hip_runtime.h>
#include <hip/hip_bf16.h>
#include <stdint.h>

#define NPTS 4096
#define NB   4
#define KNN  32
#define NKPT 15

// workspace byte offsets (all 256B-aligned)
#define OFF_IDX      0ULL            // 4*4096*32*4          = 2,097,152
#define OFF_FEAT0    2097152ULL      // 4*4097*64*4          = 4,195,328
#define OFF_WEIGHTED 6292480ULL      // 16384*960*2 (bf16)   = 31,457,280
#define OFF_HO       37749760ULL     // 16384*128*4          = 8,388,608
#define OFF_W1P      46138368ULL     // 32,768
#define OFF_W2P      46171136ULL     // 32,768
#define OFF_KPWP     46203904ULL     // 960*64*2 = 122,880 (end 46,326,784)

// d_out float offsets
#define OUT_OFF_OUT  0
#define OUT_OFF_KP   1048576
#define OUT_OFF_FUSE 1048621

// LDS unit-index XOR swizzle (16B units)
#define SBU(u) ((u) ^ (((u) >> 3) & 7))

typedef __attribute__((ext_vector_type(8))) short short8v;  // 8 bf16 (4 VGPRs)
typedef __attribute__((ext_vector_type(4))) float f32x4;    // MFMA C/D

__device__ __forceinline__ unsigned short bf16b(float f) {
  __hip_bfloat16 h = __float2bfloat16(f);
  return *(unsigned short*)&h;
}
__device__ __forceinline__ unsigned pkbf(float lo, float hi) {
  return (unsigned)bf16b(lo) | ((unsigned)bf16b(hi) << 16);
}

// ---------------- K012: neighbor search + feat0 + prepacks, one launch ----------------
// blocks [0,4096): ball query; [4096,8192): feat0; [8192,8562): prepacks/shadow/kp.
__global__ __launch_bounds__(256) void k012(const float* __restrict__ pos,
                                            const float* __restrict__ feat,
                                            const float* __restrict__ cb_w,
                                            const float* __restrict__ cb_b,
                                            const float* __restrict__ f1_w,
                                            const float* __restrict__ f2_w,
                                            const float* __restrict__ kpw,
                                            const float* __restrict__ kp_pos,
                                            int* __restrict__ idx_ws,
                                            float* __restrict__ feat0,
                                            unsigned short* __restrict__ w1p,
                                            unsigned short* __restrict__ w2p,
                                            unsigned short* __restrict__ kpwp,
                                            float* __restrict__ out_kp) {
  __shared__ float cbt[64 * 65];
  const int blk = blockIdx.x;
  if (blk < 4096) {
    // ---- ball query, first-32-by-index, f64 distances ----
    const int w = threadIdx.x >> 6, lane = threadIdx.x & 63;
    const int pt = blk * 4 + w;
    const int b = pt >> 12, n = pt & 4095;
    const float* px = pos + (size_t)b * 3 * NPTS;
    const double x0 = (double)px[n], y0 = (double)px[NPTS + n], z0 = (double)px[2 * NPTS + n];
    const double ssrc = x0 * x0 + y0 * y0 + z0 * z0;
    const double RAD = 0.1 * 2.0;
    const double R2 = RAD * RAD;
    int cnt = 0;
    int* op = idx_ws + (size_t)pt * KNN;
    for (int ch = 0; ch < 64; ++ch) {
      const int j = ch * 64 + lane;
      const double xj = (double)px[j], yj = (double)px[NPTS + j], zj = (double)px[2 * NPTS + j];
      const double dot  = x0 * xj + y0 * yj + z0 * zj;
      const double sdst = xj * xj + yj * yj + zj * zj;
      const double sq = -2.0 * dot + ssrc + sdst;
      const bool keep = !(sq > R2);
      const unsigned long long m = __ballot(keep);
      if (keep) {
        const int p = cnt + (int)__popcll(m & ((1ULL << lane) - 1ULL));
        if (p < KNN) op[p] = j;
      }
      cnt += (int)__popcll(m);
      if (cnt >= KNN) break;
    }
    const int s = cnt + lane;
    if (s < KNN) op[s] = NPTS;
    return;
  }
  if (blk < 8192) {
    // ---- feat0 = cb_w @ feat + cb_b, stored [B][N+1][64] ----
    const int t = threadIdx.x;
    #pragma unroll
    for (int q = 0; q < 16; ++q) {
      const int idx = q * 256 + t;
      const int d = idx >> 6, c = idx & 63;
      cbt[c * 65 + d] = cb_w[idx];
    }
    __syncthreads();
    const int ptl = t >> 6, d = t & 63;
    const int pt = (blk - 4096) * 4 + ptl;
    const int b = pt >> 12, n = pt & 4095;
    const float* fp = feat + (size_t)b * 64 * NPTS + n;
    float acc = 0.f;
    #pragma unroll
    for (int c = 0; c < 64; ++c) acc = fmaf(cbt[c * 65 + d], fp[(size_t)c * NPTS], acc);
    acc += cb_b[d];
    feat0[((size_t)b * (NPTS + 1) + n) * 64 + d] = acc;
    return;
  }
  // ---- prepacks ----
  int t = (blk - 8192) * 256 + threadIdx.x;
  if (t < 32768) {
    const int w = t >> 14;
    const int i = t & 16383;
    const int j = i & 7, l = (i >> 3) & 63, kc = (i >> 9) & 3, ot = i >> 11;
    const int o = ot * 16 + (l & 15);
    const int k = kc * 32 + (l >> 4) * 8 + j;
    const float* src = w ? f2_w : f1_w;
    unsigned short* dst = w ? w2p : w1p;
    dst[i] = bf16b(src[o * 128 + k]);
    return;
  }
  t -= 32768;
  if (t < 61440) {
    const int j = t & 7, l = (t >> 3) & 63, nt = (t >> 9) & 3, kc = t >> 11;  // kc 0..29
    const int k = kc * 32 + (l >> 4) * 8 + j;
    const int d = nt * 16 + (l & 15);
    kpwp[t] = bf16b(kpw[(size_t)k * 64 + d]);
    return;
  }
  t -= 61440;
  if (t < NB * 64) { int b = t >> 6, d = t & 63; feat0[((size_t)b * (NPTS + 1) + NPTS) * 64 + d] = 0.f; return; }
  t -= NB * 64;
  if (t < 45) out_kp[t] = kp_pos[t];
}

// ---------------- K3: gather + kernel-point weights + weighted bf16 [16384][960] ----------------
__global__ __launch_bounds__(64) void k3_weighted(const float* __restrict__ pos,
                                                  const int* __restrict__ idx_ws,
                                                  const float* __restrict__ feat0,
                                                  const float* __restrict__ kp_pos,
                                                  unsigned short* __restrict__ wbf) {
  __shared__ int   nidx[KNN];
  __shared__ float npx[KNN], npy[KNN], npz[KNN];
  __shared__ float kp[48];
  __shared__ float wl[KNN * 16];
  const int lane = threadIdx.x;
  const int pt = blockIdx.x;
  const int b = pt >> 12;
  if (lane < 45) kp[lane] = kp_pos[lane];
  if (lane < KNN) {
    const int ki = idx_ws[(size_t)pt * KNN + lane];
    nidx[lane] = ki;
    const bool v = ki < NPTS;
    const float* px = pos + (size_t)b * 3 * NPTS;
    npx[lane] = v ? px[ki] : 1000000.0f;
    npy[lane] = v ? px[NPTS + ki] : 1000000.0f;
    npz[lane] = v ? px[2 * NPTS + ki] : 1000000.0f;
  }
  __syncthreads();
  #pragma unroll
  for (int r = 0; r < 8; ++r) {
    const int i = r * 64 + lane;
    const int k = i >> 4, p = i & 15;
    float wv = 0.f;
    if (p < 15) {
      const float dx = npx[k] - kp[p];
      const float dy = npy[k] - kp[15 + p];
      const float dz = npz[k] - kp[30 + p];
      const float d2 = dx * dx + dy * dy + dz * dz;
      wv = fmaxf(1.0f - sqrtf(d2) / 1.2f, 0.f);
    }
    wl[i] = wv;
  }
  __syncthreads();
  float acc[16];
  #pragma unroll
  for (int p = 0; p < 16; ++p) acc[p] = 0.f;
  const float* f0 = feat0 + (size_t)b * (NPTS + 1) * 64 + lane;
  for (int k = 0; k < KNN; ++k) {
    const float f = f0[(size_t)nidx[k] * 64];
    #pragma unroll
    for (int q = 0; q < 4; ++q) {
      const float4 w4 = *(const float4*)&wl[k * 16 + q * 4];
      acc[q * 4 + 0] = fmaf(w4.x, f, acc[q * 4 + 0]);
      acc[q * 4 + 1] = fmaf(w4.y, f, acc[q * 4 + 1]);
      acc[q * 4 + 2] = fmaf(w4.z, f, acc[q * 4 + 2]);
      acc[q * 4 + 3] = fmaf(w4.w, f, acc[q * 4 + 3]);
    }
  }
  unsigned short* wp = wbf + (size_t)pt * NKPT * 64 + lane;
  #pragma unroll
  for (int p = 0; p < 15; ++p) wp[(size_t)p * 64] = bf16b(acc[p]);
}

// ---------------- K45: kpconv MFMA -> out (+feat residual) -> hO = W1b@out + b1 ----------------
// Block: 64 points (b, n0..n0+63), 256 threads / 4 waves.
__global__ __launch_bounds__(256) void k45(const unsigned short* __restrict__ wbf,
                                           const unsigned short* __restrict__ kpwp,
                                           const float* __restrict__ kp_bias,
                                           const float* __restrict__ ce_w,
                                           const float* __restrict__ ce_b,
                                           const float* __restrict__ feat,
                                           const unsigned short* __restrict__ w1p,
                                           const float* __restrict__ f1_b,
                                           float* __restrict__ out,
                                           float* __restrict__ hO) {
  __shared__ float r0[64 * 65];               // relu(kpconv) [n][c]
  __shared__ float cwt[64 * 64];              // ce_w^T [c][o]
  __shared__ unsigned short outT[64 * 74];    // bf16 out [c][n], padded
  const int t = threadIdx.x;
  const int b = blockIdx.x >> 6;
  const int n0 = (blockIdx.x & 63) * 64;
  const int wv = t >> 6, lane = t & 63;
  #pragma unroll
  for (int q = 0; q < 16; ++q) {
    const int idx = q * 256 + t;
    cwt[idx] = ce_w[(idx & 63) * 64 + (idx >> 6)];
  }
  // ---- Phase A: kpconv for this wave's 16 points ----
  const short8v* kf = (const short8v*)kpwp;
  f32x4 acc[4];
  #pragma unroll
  for (int nt = 0; nt < 4; ++nt) acc[nt] = (f32x4){0.f, 0.f, 0.f, 0.f};
  const int m0 = b * 4096 + n0 + wv * 16;
  const unsigned short* ap = wbf + (size_t)(m0 + (lane & 15)) * 960 + (lane >> 4) * 8;
  #pragma unroll 6
  for (int kc = 0; kc < 30; ++kc) {
    const short8v a = *(const short8v*)&ap[kc * 32];
    #pragma unroll
    for (int nt = 0; nt < 4; ++nt)
      acc[nt] = __builtin_amdgcn_mfma_f32_16x16x32_bf16(a, kf[(kc * 4 + nt) * 64 + lane], acc[nt], 0, 0, 0);
  }
  const int rl = wv * 16 + (lane >> 4) * 4;
  #pragma unroll
  for (int nt = 0; nt < 4; ++nt) {
    const int d = nt * 16 + (lane & 15);
    const float bv = kp_bias[d];
    #pragma unroll
    for (int r = 0; r < 4; ++r)
      r0[(rl + r) * 65 + d] = fmaxf(acc[nt][r] + bv, 0.f);
  }
  __syncthreads();
  // ---- Phase B1: out = relu(ce_w @ r0 + ce_b + feat); also outT bf16 ----
  const int nl = t & 63, og = t >> 6;
  float facc[16];
  #pragma unroll
  for (int j = 0; j < 16; ++j) facc[j] = 0.f;
  for (int c = 0; c < 64; ++c) {
    const float x = r0[nl * 65 + c];
    #pragma unroll
    for (int q = 0; q < 4; ++q) {
      const float4 w4 = *(const float4*)&cwt[c * 64 + og * 16 + q * 4];
      facc[q * 4 + 0] = fmaf(w4.x, x, facc[q * 4 + 0]);
      facc[q * 4 + 1] = fmaf(w4.y, x, facc[q * 4 + 1]);
      facc[q * 4 + 2] = fmaf(w4.z, x, facc[q * 4 + 2]);
      facc[q * 4 + 3] = fmaf(w4.w, x, facc[q * 4 + 3]);
    }
  }
  #pragma unroll
  for (int q = 0; q < 4; ++q) {
    const float4 cb4 = *(const float4*)&ce_b[og * 16 + q * 4];
    const float cbv[4] = {cb4.x, cb4.y, cb4.z, cb4.w};
    #pragma unroll
    for (int j = 0; j < 4; ++j) {
      const int o = og * 16 + q * 4 + j;
      const float fv = feat[((size_t)b * 64 + o) * 4096 + n0 + nl];
      const float v = fmaxf((facc[q * 4 + j] + cbv[j]) + fv, 0.f);
      out[((size_t)b * 64 + o) * 4096 + n0 + nl] = v;
      outT[o * 74 + nl] = bf16b(v);
    }
  }
  __syncthreads();
  // ---- Phase B2: hO[n][o2] = W1[:,64:128] @ outT + b1 (per wave: 16 n-cols) ----
  const short8v* w1f = (const short8v*)w1p;
  f32x4 hacc[8];
  #pragma unroll
  for (int ot = 0; ot < 8; ++ot) hacc[ot] = (f32x4){0.f, 0.f, 0.f, 0.f};
  const int nw = lane & 15;
  #pragma unroll
  for (int kc2 = 0; kc2 < 2; ++kc2) {
    short8v bfr;
    #pragma unroll
    for (int j = 0; j < 8; ++j)
      bfr[j] = (short)outT[(kc2 * 32 + (lane >> 4) * 8 + j) * 74 + wv * 16 + nw];
    #pragma unroll
    for (int ot = 0; ot < 8; ++ot)
      hacc[ot] = __builtin_amdgcn_mfma_f32_16x16x32_bf16(w1f[(ot * 4 + 2 + kc2) * 64 + lane], bfr, hacc[ot], 0, 0, 0);
  }
  const int rb = (lane >> 4) * 4;
  float* hp = hO + ((size_t)b * 4096 + n0 + wv * 16 + nw) * 128;
  #pragma unroll
  for (int ot = 0; ot < 8; ++ot) {
    const float4 b1 = *(const float4*)&f1_b[ot * 16 + rb];
    const float bv[4] = {b1.x, b1.y, b1.z, b1.w};
    #pragma unroll
    for (int r = 0; r < 4; ++r)
      hp[ot * 16 + rb + r] = hacc[ot][r] + bv[r];
  }
}

// ---------------- K6: fuse via bf16 MFMA; stage-1 K=64 + hO accumulator init ----------------
__global__ __launch_bounds__(256, 2) void k6_fuse(const unsigned short* __restrict__ wbf,
                                                  const float* __restrict__ hO,
                                                  const unsigned short* __restrict__ w1p,
                                                  const unsigned short* __restrict__ w2p,
                                                  const float* __restrict__ f2_b,
                                                  float* __restrict__ fuse) {
  __shared__ __attribute__((aligned(16))) unsigned short SB[16384];  // 32 KB
  __shared__ __attribute__((aligned(16))) float hOS[12 * 128];       // 6 KB
  const int t = threadIdx.x;
  const int blk = blockIdx.x;
  const int b = blk / 480;
  const int ml0 = (blk - b * 480) * 128;
  const size_t M0 = (size_t)blk * 128;
  const int wv = t >> 6, lane = t & 63;
  const short8v* w1f = (const short8v*)w1p;
  const short8v* w2f = (const short8v*)w2p;

  // early W1 top-half fragment loads (16) — latency hidden under staging
  short8v w1r[16];
  #pragma unroll
  for (int ot = 0; ot < 8; ++ot)
    #pragma unroll
    for (int kc = 0; kc < 2; ++kc)
      w1r[ot * 2 + kc] = w1f[(ot * 4 + kc) * 64 + lane];

  // stage Xw (c=0..63): bf16 bit-copy from weighted
  #pragma unroll
  for (int q = 0; q < 4; ++q) {
    const int chunk = q * 256 + t;
    const int m = chunk >> 3, a = chunk & 7;
    const uint4 pk = *(const uint4*)&wbf[(M0 + m) * 64 + a * 8];
    const int kc = a >> 2, hi = a & 3;
    const int u = ((m >> 4) * 4 + kc) * 64 + hi * 16 + (m & 15);
    *(uint4*)&SB[SBU(u) * 8] = pk;
  }
  // stage hO rows for this tile's n-range
  const int nmin = ml0 / 15;
  #pragma unroll
  for (int q = 0; q < 6; ++q) {
    const int idx = q * 256 + t;
    const int row = idx >> 7, o = idx & 127;
    int n = nmin + row;
    if (n > 4095) n = 4095;
    hOS[idx] = hO[((size_t)b * 4096 + n) * 128 + o];
  }
  __syncthreads();

  // this wave's Xw B-fragments (K=64: kc 0,1)
  short8v xf[4];
  #pragma unroll
  for (int mt = 0; mt < 2; ++mt)
    #pragma unroll
    for (int kc = 0; kc < 2; ++kc) {
      const int u = ((wv * 2 + mt) * 4 + kc) * 64 + lane;
      xf[mt * 2 + kc] = *(const short8v*)&SB[SBU(u) * 8];
    }

  const int rb = (lane >> 4) * 4;
  const int dnA = (ml0 + wv * 32 + (lane & 15)) / 15 - nmin;
  const int dnB = (ml0 + wv * 32 + 16 + (lane & 15)) / 15 - nmin;
  f32x4 acc[8][2];
  #pragma unroll
  for (int ot = 0; ot < 8; ++ot) {
    acc[ot][0] = *(const f32x4*)&hOS[dnA * 128 + ot * 16 + rb];
    acc[ot][1] = *(const f32x4*)&hOS[dnB * 128 + ot * 16 + rb];
  }
  // stage 1: acc += W1a @ Xw  (K=64)
  #pragma unroll
  for (int kc = 0; kc < 2; ++kc) {
    #pragma unroll
    for (int ot = 0; ot < 8; ++ot) {
      acc[ot][0] = __builtin_amdgcn_mfma_f32_16x16x32_bf16(w1r[ot * 2 + kc], xf[kc],     acc[ot][0], 0, 0, 0);
      acc[ot][1] = __builtin_amdgcn_mfma_f32_16x16x32_bf16(w1r[ot * 2 + kc], xf[2 + kc], acc[ot][1], 0, 0, 0);
    }
  }
  // issue W2 loads — latency covered by H epilogue
  short8v w2r[32];
  #pragma unroll
  for (int i = 0; i < 32; ++i) w2r[i] = w2f[i * 64 + lane];

  // H epilogue (relu only; b1 folded into hO) -> wave's own SB region
  #pragma unroll
  for (int ot = 0; ot < 8; ++ot) {
    const int o0 = ot * 16 + rb;
    const int kc = o0 >> 5, hi = (o0 >> 3) & 3, j0 = o0 & 7;
    #pragma unroll
    for (int mt = 0; mt < 2; ++mt) {
      const f32x4 h = acc[ot][mt];
      const float h0 = fmaxf(h[0], 0.f);
      const float h1 = fmaxf(h[1], 0.f);
      const float h2 = fmaxf(h[2], 0.f);
      const float h3 = fmaxf(h[3], 0.f);
      const int u = ((wv * 2 + mt) * 4 + kc) * 64 + hi * 16 + (lane & 15);
      uint2 pk;
      pk.x = pkbf(h0, h1);
      pk.y = pkbf(h2, h3);
      *(uint2*)&SB[SBU(u) * 8 + j0] = pk;
    }
  }
  // read H fragments (K=128: kc 0..3)
  short8v hf[8];
  #pragma unroll
  for (int mt = 0; mt < 2; ++mt)
    #pragma unroll
    for (int kc = 0; kc < 4; ++kc) {
      const int u = ((wv * 2 + mt) * 4 + kc) * 64 + lane;
      hf[mt * 4 + kc] = *(const short8v*)&SB[SBU(u) * 8];
    }
  // stage 2
  #pragma unroll
  for (int ot = 0; ot < 8; ++ot) {
    acc[ot][0] = (f32x4){0.f, 0.f, 0.f, 0.f};
    acc[ot][1] = (f32x4){0.f, 0.f, 0.f, 0.f};
  }
  #pragma unroll
  for (int kc = 0; kc < 4; ++kc) {
    #pragma unroll
    for (int ot = 0; ot < 8; ++ot) {
      acc[ot][0] = __builtin_amdgcn_mfma_f32_16x16x32_bf16(w2r[ot * 4 + kc], hf[kc],     acc[ot][0], 0, 0, 0);
      acc[ot][1] = __builtin_amdgcn_mfma_f32_16x16x32_bf16(w2r[ot * 4 + kc], hf[4 + kc], acc[ot][1], 0, 0, 0);
    }
  }
  // F epilogue -> global
  float* fp0 = fuse + (size_t)b * 128 * 61440 + ml0 + wv * 32 + (lane & 15);
  #pragma unroll
  for (int ot = 0; ot < 8; ++ot) {
    const int o0 = ot * 16 + rb;
    const float4 b2 = *(const float4*)&f2_b[o0];
    const float bv[4] = {b2.x, b2.y, b2.z, b2.w};
    #pragma unroll
    for (int mt = 0; mt < 2; ++mt) {
      const f32x4 vacc = acc[ot][mt];
      #pragma unroll
      for (int r = 0; r < 4; ++r)
        fp0[(size_t)(o0 + r) * 61440 + mt * 16] = fmaxf(vacc[r] + bv[r], 0.f);
    }
  }
}

extern "C" void kernel_launch(void* const* d_in, const int* in_sizes, int n_in,
                              void* d_out, int out_size, void* d_ws, size_t ws_size,
                              hipStream_t stream) {
  const float* pos     = (const float*)d_in[0];
  const float* feat    = (const float*)d_in[1];
  const float* kp_pos  = (const float*)d_in[2];
  const float* cb_w    = (const float*)d_in[3];
  const float* cb_b    = (const float*)d_in[4];
  const float* kpw     = (const float*)d_in[5];
  const float* kp_bias = (const float*)d_in[6];
  const float* ce_w    = (const float*)d_in[7];
  const float* ce_b    = (const float*)d_in[8];
  const float* f1_w    = (const float*)d_in[9];
  const float* f1_b    = (const float*)d_in[10];
  const float* f2_w    = (const float*)d_in[11];
  const float* f2_b    = (const float*)d_in[12];
  float* out = (float*)d_out;
  char* ws = (char*)d_ws;
  int*   idx_ws   = (int*)(ws + OFF_IDX);
  float* feat0    = (float*)(ws + OFF_FEAT0);
  unsigned short* wbf  = (unsigned short*)(ws + OFF_WEIGHTED);
  float* hO       = (float*)(ws + OFF_HO);
  unsigned short* w1p  = (unsigned short*)(ws + OFF_W1P);
  unsigned short* w2p  = (unsigned short*)(ws + OFF_W2P);
  unsigned short* kpwp = (unsigned short*)(ws + OFF_KPWP);

  k012<<<8562, 256, 0, stream>>>(pos, feat, cb_w, cb_b, f1_w, f2_w, kpw, kp_pos,
                                 idx_ws, feat0, w1p, w2p, kpwp, out + OUT_OFF_KP);
  k3_weighted<<<16384, 64, 0, stream>>>(pos, idx_ws, feat0, kp_pos, wbf);
  k45<<<256, 256, 0, stream>>>(wbf, kpwp, kp_bias, ce_w, ce_b, feat, w1p, f1_b,
                               out + OUT_OFF_OUT, hO);
  k6_fuse<<<1920, 256, 0, stream>>>(wbf, hO, w1p, w2p, f2_b, out + OUT_OFF_FUSE);
}